// Round 5
// baseline (435.392 us; speedup 1.0000x reference)
//
#include <hip/hip_runtime.h>
#include <math.h>

// Problem constants (B=1): S=4096, D=128, NHEADS=4, hd=32, N_COE=50, N_SCALES=4, THRE=5
//
// ws layout (floats):
//   eig  @ 0        (4096*128   = 524288)
//   qkv  @ 524288   (4096*384   = 1572864)
//   Oe   @ 2097152  (8*4096*128 = 4194304)   exp-weighted V partials, 8 key-slot copies
//   E    @ 6291456  (8*4*4096   = 131072)    exp sums, [ks][h][q]
//   xsum @ 6422528  (128)
//   coef @ 6422656  (104)
// total ~25.7 MB

#define KSPLIT 8

// ---------------- K1: sine encoding + eig = eeig @ W + b (8 rows/block, 512 blocks) ----------------
__global__ __launch_bounds__(256) void k_eig(const float* __restrict__ eve,
    const float* __restrict__ W, const float* __restrict__ bias,
    float* __restrict__ eig)
{
    __shared__ __align__(16) float se[8][132];    // [0..63]=sin, [64..127]=cos, [128]=e
    const int t = threadIdx.x;
    const int r0 = blockIdx.x * 8;
    {
        const int r = t >> 5, l = t & 31;
        const float e = eve[r0 + r];
        if (l == 0) se[r][128] = e;
        const float e100 = e * 100.0f;
        #pragma unroll
        for (int jj = 0; jj < 2; ++jj) {
            const int j = l * 2 + jj;             // 0..63
            const float div = expf(-0.07195578415606394f * (float)(2 * j));
            const float pe = e100 * div;
            se[r][j]      = sinf(pe);
            se[r][64 + j] = cosf(pe);
        }
    }
    __syncthreads();
    const int c = t & 127;
    const int rg = t >> 7;                        // 0..1; rows rg+2i, i<4
    float acc[4];
    {
        const float w0 = W[c];                    // W row 0 pairs with raw e
        #pragma unroll
        for (int i = 0; i < 4; ++i) acc[i] = se[rg + 2 * i][128] * w0;
    }
    for (int k = 0; k < 128; k += 4) {            // se[.][k] pairs W[k+1]
        const float w0 = W[(k + 1) * 128 + c];
        const float w1 = W[(k + 2) * 128 + c];
        const float w2 = W[(k + 3) * 128 + c];
        const float w3 = W[(k + 4) * 128 + c];
        #pragma unroll
        for (int i = 0; i < 4; ++i) {
            const float4 x = *(const float4*)&se[rg + 2 * i][k];
            float a = acc[i];
            a = fmaf(x.x, w0, a);
            a = fmaf(x.y, w1, a);
            a = fmaf(x.z, w2, a);
            a = fmaf(x.w, w3, a);
            acc[i] = a;
        }
    }
    const float bb = bias[c];
    #pragma unroll
    for (int i = 0; i < 4; ++i) eig[(r0 + rg + 2 * i) * 128 + c] = acc[i] + bb;
}

// ---------------- K2: LN1 + qkv = ln(eig) @ in_W + in_b (8 rows/block, 512 blocks) ----------------
__global__ __launch_bounds__(256) void k_qkv(const float* __restrict__ eig,
    const float* __restrict__ g, const float* __restrict__ b,
    const float* __restrict__ inW, const float* __restrict__ inb,
    float* __restrict__ qkv)
{
    __shared__ __align__(16) float xn[8][128];
    __shared__ float red1[8][32];
    __shared__ float red2[8][32];
    const int t = threadIdx.x;
    const int r0 = blockIdx.x * 8;
    const int r = t >> 5, l = t & 31;
    float v[4];
    {
        float s = 0.f, ss = 0.f;
        #pragma unroll
        for (int m = 0; m < 4; ++m) {
            const float x = eig[(r0 + r) * 128 + l + 32 * m];
            v[m] = x; s += x; ss += x * x;
        }
        red1[r][l] = s; red2[r][l] = ss;
    }
    __syncthreads();
    for (int o = 16; o > 0; o >>= 1) {
        if (l < o) { red1[r][l] += red1[r][l + o]; red2[r][l] += red2[r][l + o]; }
        __syncthreads();
    }
    {
        const float mean = red1[r][0] * (1.f / 128.f);
        const float var  = red2[r][0] * (1.f / 128.f) - mean * mean;
        const float inv  = 1.f / sqrtf(var + 1e-5f);
        #pragma unroll
        for (int m = 0; m < 4; ++m) {
            const int col = l + 32 * m;
            xn[r][col] = (v[m] - mean) * inv * g[col] + b[col];
        }
    }
    __syncthreads();
    const int cbase = t & 127;
    const int rg = t >> 7;
    float acc[3][4];
    #pragma unroll
    for (int p = 0; p < 3; ++p) {
        const float bb = inb[p * 128 + cbase];
        #pragma unroll
        for (int i = 0; i < 4; ++i) acc[p][i] = bb;
    }
    for (int k = 0; k < 128; k += 4) {
        float4 xv[4];
        #pragma unroll
        for (int i = 0; i < 4; ++i) xv[i] = *(const float4*)&xn[rg + 2 * i][k];
        #pragma unroll
        for (int p = 0; p < 3; ++p) {
            const int c = p * 128 + cbase;
            const float w0 = inW[(k + 0) * 384 + c];
            const float w1 = inW[(k + 1) * 384 + c];
            const float w2 = inW[(k + 2) * 384 + c];
            const float w3 = inW[(k + 3) * 384 + c];
            #pragma unroll
            for (int i = 0; i < 4; ++i) {
                float a = acc[p][i];
                a = fmaf(xv[i].x, w0, a);
                a = fmaf(xv[i].y, w1, a);
                a = fmaf(xv[i].z, w2, a);
                a = fmaf(xv[i].w, w3, a);
                acc[p][i] = a;
            }
        }
    }
    #pragma unroll
    for (int p = 0; p < 3; ++p)
        #pragma unroll
        for (int i = 0; i < 4; ++i)
            qkv[(r0 + rg + 2 * i) * 384 + p * 128 + cbase] = acc[p][i];
}

// ---------------- K3: attention, no-max softmax partials, 8-way key split ----------------
// Wave = 64 queries (lanes) x 128-key range. Key range derived from readfirstlane(waveid)
// + blockIdx only -> K/V addresses provably wave-uniform -> s_load broadcast path.
// Scores bounded (|s|<~65) so exp without max-subtraction is exact-safe in fp32; partials
// linear: E = sum exp(s), Oe = sum exp(s)*V. 4 waves merge via LDS atomics; block -> slot ks.
__global__ __launch_bounds__(256, 4) void k_attn(const float* __restrict__ qkv,
    const int* __restrict__ sele, float* __restrict__ Oe, float* __restrict__ E)
{
    __shared__ float sOe[64][33];
    __shared__ float sE[64];
    const int t = threadIdx.x;
    const int lane = t & 63;
    const int wv = __builtin_amdgcn_readfirstlane(t >> 6);  // 0..3, wave-uniform SGPR
    const int qt = blockIdx.x;            // 64 q-tiles of 64
    const int h  = blockIdx.y;            // 4 heads
    const int ks = blockIdx.z;            // 8 key slots
    const int sq = qt * 64 + lane;
    const int nk = sele[0];
    for (int i = t; i < 64 * 33; i += 256) ((float*)sOe)[i] = 0.f;
    if (t < 64) sE[t] = 0.f;
    __syncthreads();

    const float scl = 0.17677669529663687f;  // 1/sqrt(32)
    float q[32];
    {
        const float* __restrict__ qr = qkv + (size_t)sq * 384 + h * 32;
        #pragma unroll
        for (int d = 0; d < 32; ++d) q[d] = qr[d] * scl;
    }
    float lsum = 0.f;
    float acc[32];
    #pragma unroll
    for (int d = 0; d < 32; ++d) acc[d] = 0.f;

    const int k0 = ks * 512 + wv * 128;
    for (int kc = k0; kc < k0 + 128; kc += 4) {
        float p[4];
        #pragma unroll
        for (int c = 0; c < 4; ++c) {
            const float* __restrict__ kr = qkv + (size_t)(kc + c) * 384 + 128 + h * 32;
            float s = 0.f;
            #pragma unroll
            for (int d = 0; d < 32; ++d) s = fmaf(q[d], kr[d], s);
            p[c] = (kc + c < nk) ? __expf(s) : 0.f;
        }
        lsum += (p[0] + p[1]) + (p[2] + p[3]);
        #pragma unroll
        for (int c = 0; c < 4; ++c) {
            const float* __restrict__ vr = qkv + (size_t)(kc + c) * 384 + 256 + h * 32;
            const float pc = p[c];
            #pragma unroll
            for (int d = 0; d < 32; ++d) acc[d] = fmaf(pc, vr[d], acc[d]);
        }
    }
    atomicAdd(&sE[lane], lsum);
    #pragma unroll
    for (int d = 0; d < 32; ++d) atomicAdd(&sOe[lane][d], acc[d]);
    __syncthreads();
    float* __restrict__ oeg = Oe + ((size_t)ks * 4096 + qt * 64) * 128 + h * 32;
    for (int i = t; i < 2048; i += 256) {
        const int q2 = i >> 5, d = i & 31;
        oeg[(size_t)q2 * 128 + d] = sOe[q2][d];
    }
    if (t < 64) E[((size_t)ks * 4 + h) * 4096 + qt * 64 + t] = sE[t];
}

// ---------------- K4: fold Oe/E + out-proj + residual + LN2 + FFN + residual + column-sum ----------------
__global__ __launch_bounds__(256) void k_ffn(const float* __restrict__ eig,
    const float* __restrict__ Oe, const float* __restrict__ E,
    const float* __restrict__ outW, const float* __restrict__ outb,
    const float* __restrict__ lg, const float* __restrict__ lb,
    const float* __restrict__ W1, const float* __restrict__ b1,
    const float* __restrict__ W2, const float* __restrict__ b2,
    const int* __restrict__ sele, float* __restrict__ xsum)
{
    __shared__ __align__(16) float sA[8][128];    // attention O rows, later gelu(h)
    __shared__ __align__(16) float x2[8][128];    // residual stream
    __shared__ __align__(16) float xn[8][128];    // LN2 output
    __shared__ float red1[8][32];
    __shared__ float red2[8][32];
    __shared__ float sEr[8][4];
    __shared__ float colsum[2][128];
    const int t = threadIdx.x;
    const int r0 = blockIdx.x * 8;
    const int r = t >> 5, l = t & 31;
    if (l < 4) {                                   // per-(row,head) reciprocal exp-sum
        float es = 0.f;
        #pragma unroll
        for (int ks = 0; ks < KSPLIT; ++ks)
            es += E[((size_t)ks * 4 + l) * 4096 + r0 + r];
        sEr[r][l] = 1.f / es;
    }
    __syncthreads();
    #pragma unroll
    for (int m = 0; m < 4; ++m) {                  // fold 8 slots -> O row
        const int col = l + 32 * m;
        float v = 0.f;
        #pragma unroll
        for (int ks = 0; ks < KSPLIT; ++ks)
            v += Oe[((size_t)ks * 4096 + r0 + r) * 128 + col];
        sA[r][col] = v * sEr[r][col >> 5];
    }
    __syncthreads();
    const int c = t & 127;
    const int rg = t >> 7;
    {   // out projection + residual
        float acc[4];
        const float bb = outb[c];
        #pragma unroll
        for (int i = 0; i < 4; ++i) acc[i] = bb;
        for (int k = 0; k < 128; k += 4) {
            const float w0 = outW[(k + 0) * 128 + c];
            const float w1 = outW[(k + 1) * 128 + c];
            const float w2 = outW[(k + 2) * 128 + c];
            const float w3 = outW[(k + 3) * 128 + c];
            #pragma unroll
            for (int i = 0; i < 4; ++i) {
                const float4 x = *(const float4*)&sA[rg + 2 * i][k];
                float a = acc[i];
                a = fmaf(x.x, w0, a);
                a = fmaf(x.y, w1, a);
                a = fmaf(x.z, w2, a);
                a = fmaf(x.w, w3, a);
                acc[i] = a;
            }
        }
        #pragma unroll
        for (int i = 0; i < 4; ++i)
            x2[rg + 2 * i][c] = eig[(r0 + rg + 2 * i) * 128 + c] + acc[i];
    }
    __syncthreads();
    {   // LN2
        float s = 0.f, ss = 0.f;
        float v[4];
        #pragma unroll
        for (int m = 0; m < 4; ++m) {
            const float x = x2[r][l + 32 * m];
            v[m] = x; s += x; ss += x * x;
        }
        red1[r][l] = s; red2[r][l] = ss;
        __syncthreads();
        for (int o = 16; o > 0; o >>= 1) {
            if (l < o) { red1[r][l] += red1[r][l + o]; red2[r][l] += red2[r][l + o]; }
            __syncthreads();
        }
        const float mean = red1[r][0] * (1.f / 128.f);
        const float var  = red2[r][0] * (1.f / 128.f) - mean * mean;
        const float inv  = 1.f / sqrtf(var + 1e-5f);
        #pragma unroll
        for (int m = 0; m < 4; ++m) {
            const int col = l + 32 * m;
            xn[r][col] = (v[m] - mean) * inv * lg[col] + lb[col];
        }
    }
    __syncthreads();
    {   // FFN1 + exact gelu -> sA
        float acc[4];
        const float bb = b1[c];
        #pragma unroll
        for (int i = 0; i < 4; ++i) acc[i] = bb;
        for (int k = 0; k < 128; k += 4) {
            const float w0 = W1[(k + 0) * 128 + c];
            const float w1 = W1[(k + 1) * 128 + c];
            const float w2 = W1[(k + 2) * 128 + c];
            const float w3 = W1[(k + 3) * 128 + c];
            #pragma unroll
            for (int i = 0; i < 4; ++i) {
                const float4 x = *(const float4*)&xn[rg + 2 * i][k];
                float a = acc[i];
                a = fmaf(x.x, w0, a);
                a = fmaf(x.y, w1, a);
                a = fmaf(x.z, w2, a);
                a = fmaf(x.w, w3, a);
                acc[i] = a;
            }
        }
        __syncthreads();
        #pragma unroll
        for (int i = 0; i < 4; ++i) {
            const float x = acc[i];
            sA[rg + 2 * i][c] = 0.5f * x * (1.f + erff(x * 0.70710678118654752f));
        }
    }
    __syncthreads();
    {   // FFN2 + residual + masked column sum
        float acc[4];
        const float bb = b2[c];
        #pragma unroll
        for (int i = 0; i < 4; ++i) acc[i] = bb;
        for (int k = 0; k < 128; k += 4) {
            const float w0 = W2[(k + 0) * 128 + c];
            const float w1 = W2[(k + 1) * 128 + c];
            const float w2 = W2[(k + 2) * 128 + c];
            const float w3 = W2[(k + 3) * 128 + c];
            #pragma unroll
            for (int i = 0; i < 4; ++i) {
                const float4 x = *(const float4*)&sA[rg + 2 * i][k];
                float a = acc[i];
                a = fmaf(x.x, w0, a);
                a = fmaf(x.y, w1, a);
                a = fmaf(x.z, w2, a);
                a = fmaf(x.w, w3, a);
                acc[i] = a;
            }
        }
        const int nsel = sele[0];
        float local = 0.f;
        #pragma unroll
        for (int i = 0; i < 4; ++i) {
            const float ef = x2[rg + 2 * i][c] + acc[i];
            if (r0 + rg + 2 * i < nsel) local += ef;
        }
        colsum[rg][c] = local;
    }
    __syncthreads();
    if (rg == 0) atomicAdd(&xsum[c], colsum[0][c] + colsum[1][c]);
}

// ---------------- K5: pooled coefficients ----------------
__global__ __launch_bounds__(128) void k_coef(const float* __restrict__ xsum,
    const float* __restrict__ dscW, const float* __restrict__ dscb,
    const float* __restrict__ dwvW, const float* __restrict__ dwvb,
    const float* __restrict__ dssW, const float* __restrict__ dssb,
    const int* __restrict__ len, const int* __restrict__ sele,
    float* __restrict__ coef)
{
    __shared__ float xs[128];
    __shared__ float csc[50], cwv[50];
    __shared__ float s2[2];
    const int t = threadIdx.x;
    xs[t] = xsum[t];
    __syncthreads();
    const float invl = 1.f / ((float)len[0] + 1e-8f);
    const float ns = (float)sele[0];
    if (t < 50) {
        float a = ns * dscb[t];
        for (int k = 0; k < 128; ++k) a = fmaf(xs[k], dscW[k * 50 + t], a);
        a *= invl;
        csc[t] = 1.f / (1.f + expf(-a));
    } else if (t >= 64 && t < 114) {
        const int j = t - 64;
        float a = ns * dwvb[j];
        for (int k = 0; k < 128; ++k) a = fmaf(xs[k], dwvW[k * 50 + j], a);
        a *= invl;
        cwv[j] = 1.f / (1.f + expf(-a));
    } else if (t >= 114 && t < 118) {
        const int j = t - 114;
        float a = ns * dssb[j];
        for (int k = 0; k < 128; ++k) a = fmaf(xs[k], dssW[k * 4 + j], a);
        a *= invl;
        coef[100 + j] = (1.f / (1.f + expf(-a))) * 5.0f;  // THRE
    }
    __syncthreads();
    if (t == 0) { float s = 0.f; for (int i2 = 0; i2 < 50; ++i2) s += csc[i2]; s2[0] = s; }
    if (t == 1) { float s = 0.f; for (int i2 = 0; i2 < 50; ++i2) s += cwv[i2]; s2[1] = s; }
    __syncthreads();
    if (t < 50) {
        coef[t]      = csc[t] / (s2[0] + 1e-8f);
        coef[50 + t] = cwv[t] / (s2[1] + 1e-8f);
    }
}

// ---------------- K6: Chebyshev bases + combine + normalize ----------------
__global__ __launch_bounds__(256) void k_out(const float* __restrict__ eve,
    const float* __restrict__ coef, float* __restrict__ out)
{
    __shared__ float csc[50], cwv[50], cs[4];
    const int t = threadIdx.x;
    if (t < 50) csc[t] = coef[t];
    else if (t < 100) cwv[t - 50] = coef[t];
    else if (t < 104) cs[t - 100] = coef[t];
    __syncthreads();
    const int s = blockIdx.x * 256 + t;
    const float e = eve[s];
    float vals[5];
    {   // scaling: [T1, T3, ..., T99](e-1); 0.5*(1-T)
        const float y = e - 1.f;
        float te = 1.f, to = y;
        float a = csc[0] * (0.5f * (1.f - to));
        const float y2 = 2.f * y;
        for (int i = 1; i < 50; ++i) {
            te = fmaf(y2, to, -te);
            to = fmaf(y2, te, -to);
            a = fmaf(csc[i], 0.5f * (1.f - to), a);
        }
        vals[0] = a;
    }
    #pragma unroll
    for (int j = 0; j < 4; ++j) {  // wavelet: [T0, T2, ..., T98](fsw-1)
        float f = e * cs[j];
        if (f > 2.f) f = 0.f;
        const float y = f - 1.f;
        float te = 1.f, to = y;
        float a = cwv[0] * (0.5f * (1.f - te));
        const float y2 = 2.f * y;
        for (int i = 1; i < 50; ++i) {
            te = fmaf(y2, to, -te);
            to = fmaf(y2, te, -to);
            a = fmaf(cwv[i], 0.5f * (1.f - te), a);
        }
        vals[1 + j] = a;
    }
    float n2 = 0.f;
    #pragma unroll
    for (int k = 0; k < 5; ++k) n2 += vals[k] * vals[k];
    const float invn = 1.f / (sqrtf(n2) + 1e-8f);
    #pragma unroll
    for (int k = 0; k < 5; ++k) out[s * 5 + k] = vals[k] * invn;
}

extern "C" void kernel_launch(void* const* d_in, const int* in_sizes, int n_in,
                              void* d_out, int out_size, void* d_ws, size_t ws_size,
                              hipStream_t stream) {
    const float* eve  = (const float*)d_in[0];
    const int*   len  = (const int*)d_in[1];
    const int*   sele = (const int*)d_in[2];
    const float* eigW = (const float*)d_in[3];
    const float* eigB = (const float*)d_in[4];
    const float* mlg  = (const float*)d_in[5];
    const float* mlb  = (const float*)d_in[6];
    const float* inW  = (const float*)d_in[7];
    const float* inb  = (const float*)d_in[8];
    const float* outW = (const float*)d_in[9];
    const float* outb = (const float*)d_in[10];
    const float* flg  = (const float*)d_in[11];
    const float* flb  = (const float*)d_in[12];
    const float* W1   = (const float*)d_in[13];
    const float* b1   = (const float*)d_in[14];
    const float* W2   = (const float*)d_in[15];
    const float* b2   = (const float*)d_in[16];
    const float* dscW = (const float*)d_in[17];
    const float* dscb = (const float*)d_in[18];
    const float* dwvW = (const float*)d_in[19];
    const float* dwvb = (const float*)d_in[20];
    const float* dssW = (const float*)d_in[21];
    const float* dssb = (const float*)d_in[22];

    float* ws   = (float*)d_ws;
    float* eig  = ws;
    float* qkv  = ws + 524288;
    float* Oe   = ws + 2097152;
    float* E    = ws + 6291456;
    float* xsum = ws + 6422528;
    float* coef = ws + 6422656;
    float* out  = (float*)d_out;

    hipMemsetAsync(xsum, 0, 128 * sizeof(float), stream);
    k_eig <<<512, 256, 0, stream>>>(eve, eigW, eigB, eig);
    k_qkv <<<512, 256, 0, stream>>>(eig, mlg, mlb, inW, inb, qkv);
    k_attn<<<dim3(64, 4, KSPLIT), 256, 0, stream>>>(qkv, sele, Oe, E);
    k_ffn <<<512, 256, 0, stream>>>(eig, Oe, E, outW, outb, flg, flb, W1, b1, W2, b2, sele, xsum);
    k_coef<<<1, 128, 0, stream>>>(xsum, dscW, dscb, dwvW, dwvb, dssW, dssb, len, sele, coef);
    k_out <<<16, 256, 0, stream>>>(eve, coef, out);
}

// Round 6
// 232.711 us; speedup vs baseline: 1.8710x; 1.8710x over previous
//
#include <hip/hip_runtime.h>
#include <math.h>

// Problem constants (B=1): S=4096, D=128, NHEADS=4, hd=32, N_COE=50, N_SCALES=4, THRE=5
//
// ws layout (floats):
//   eig  @ 0        (4096*128   = 524288)
//   qkv  @ 524288   (4096*384   = 1572864)
//   Oe   @ 2097152  (4*4096*128 = 2097152)   exp-weighted V partials (f32 MFMA accum), 4 key slots
//   E    @ 4194304  (4*4*4096   = 65536)     exp sums, [ks][h][q]
//   xsum @ 4259840  (128)
//   coef @ 4259968  (104)
// total ~17 MB

#define KSPLIT 4

typedef __attribute__((ext_vector_type(8))) short short8;   // 8 bf16 (4 VGPRs)
typedef __attribute__((ext_vector_type(4))) float f32x4;

__device__ inline unsigned short f2bf(float x) {            // RNE f32->bf16 bits
    unsigned u = __float_as_uint(x);
    return (unsigned short)((u + 0x7FFFu + ((u >> 16) & 1u)) >> 16);
}
__device__ inline float bf2f(unsigned short h) { return __uint_as_float(((unsigned)h) << 16); }

// ---------------- K1: sine encoding + eig = eeig @ W + b (8 rows/block, 512 blocks) ----------------
__global__ __launch_bounds__(256) void k_eig(const float* __restrict__ eve,
    const float* __restrict__ W, const float* __restrict__ bias,
    float* __restrict__ eig)
{
    __shared__ __align__(16) float se[8][132];    // [0..63]=sin, [64..127]=cos, [128]=e
    const int t = threadIdx.x;
    const int r0 = blockIdx.x * 8;
    {
        const int r = t >> 5, l = t & 31;
        const float e = eve[r0 + r];
        if (l == 0) se[r][128] = e;
        const float e100 = e * 100.0f;
        #pragma unroll
        for (int jj = 0; jj < 2; ++jj) {
            const int j = l * 2 + jj;             // 0..63
            const float div = expf(-0.07195578415606394f * (float)(2 * j));
            const float pe = e100 * div;
            se[r][j]      = sinf(pe);
            se[r][64 + j] = cosf(pe);
        }
    }
    __syncthreads();
    const int c = t & 127;
    const int rg = t >> 7;                        // 0..1; rows rg+2i, i<4
    float acc[4];
    {
        const float w0 = W[c];                    // W row 0 pairs with raw e
        #pragma unroll
        for (int i = 0; i < 4; ++i) acc[i] = se[rg + 2 * i][128] * w0;
    }
    for (int k = 0; k < 128; k += 4) {            // se[.][k] pairs W[k+1]
        const float w0 = W[(k + 1) * 128 + c];
        const float w1 = W[(k + 2) * 128 + c];
        const float w2 = W[(k + 3) * 128 + c];
        const float w3 = W[(k + 4) * 128 + c];
        #pragma unroll
        for (int i = 0; i < 4; ++i) {
            const float4 x = *(const float4*)&se[rg + 2 * i][k];
            float a = acc[i];
            a = fmaf(x.x, w0, a);
            a = fmaf(x.y, w1, a);
            a = fmaf(x.z, w2, a);
            a = fmaf(x.w, w3, a);
            acc[i] = a;
        }
    }
    const float bb = bias[c];
    #pragma unroll
    for (int i = 0; i < 4; ++i) eig[(r0 + rg + 2 * i) * 128 + c] = acc[i] + bb;
}

// ---------------- K2: LN1 + qkv = ln(eig) @ in_W + in_b (8 rows/block, 512 blocks) ----------------
__global__ __launch_bounds__(256) void k_qkv(const float* __restrict__ eig,
    const float* __restrict__ g, const float* __restrict__ b,
    const float* __restrict__ inW, const float* __restrict__ inb,
    float* __restrict__ qkv)
{
    __shared__ __align__(16) float xn[8][128];
    __shared__ float red1[8][32];
    __shared__ float red2[8][32];
    const int t = threadIdx.x;
    const int r0 = blockIdx.x * 8;
    const int r = t >> 5, l = t & 31;
    float v[4];
    {
        float s = 0.f, ss = 0.f;
        #pragma unroll
        for (int m = 0; m < 4; ++m) {
            const float x = eig[(r0 + r) * 128 + l + 32 * m];
            v[m] = x; s += x; ss += x * x;
        }
        red1[r][l] = s; red2[r][l] = ss;
    }
    __syncthreads();
    for (int o = 16; o > 0; o >>= 1) {
        if (l < o) { red1[r][l] += red1[r][l + o]; red2[r][l] += red2[r][l + o]; }
        __syncthreads();
    }
    {
        const float mean = red1[r][0] * (1.f / 128.f);
        const float var  = red2[r][0] * (1.f / 128.f) - mean * mean;
        const float inv  = 1.f / sqrtf(var + 1e-5f);
        #pragma unroll
        for (int m = 0; m < 4; ++m) {
            const int col = l + 32 * m;
            xn[r][col] = (v[m] - mean) * inv * g[col] + b[col];
        }
    }
    __syncthreads();
    const int cbase = t & 127;
    const int rg = t >> 7;
    float acc[3][4];
    #pragma unroll
    for (int p = 0; p < 3; ++p) {
        const float bb = inb[p * 128 + cbase];
        #pragma unroll
        for (int i = 0; i < 4; ++i) acc[p][i] = bb;
    }
    for (int k = 0; k < 128; k += 4) {
        float4 xv[4];
        #pragma unroll
        for (int i = 0; i < 4; ++i) xv[i] = *(const float4*)&xn[rg + 2 * i][k];
        #pragma unroll
        for (int p = 0; p < 3; ++p) {
            const int c = p * 128 + cbase;
            const float w0 = inW[(k + 0) * 384 + c];
            const float w1 = inW[(k + 1) * 384 + c];
            const float w2 = inW[(k + 2) * 384 + c];
            const float w3 = inW[(k + 3) * 384 + c];
            #pragma unroll
            for (int i = 0; i < 4; ++i) {
                float a = acc[p][i];
                a = fmaf(xv[i].x, w0, a);
                a = fmaf(xv[i].y, w1, a);
                a = fmaf(xv[i].z, w2, a);
                a = fmaf(xv[i].w, w3, a);
                acc[p][i] = a;
            }
        }
    }
    #pragma unroll
    for (int p = 0; p < 3; ++p)
        #pragma unroll
        for (int i = 0; i < 4; ++i)
            qkv[(r0 + rg + 2 * i) * 384 + p * 128 + cbase] = acc[p][i];
}

// ---------------- K3: MFMA flash attention (no-max linear partials) ----------------
// Block = (qblock of 64 queries, head, key-slot of 1024). 4 waves = 4 q-subtiles of 16.
// QK^T: mfma_f32_16x16x32_bf16 with split-2 bf16 (S = Qhi*Khi + Qhi*Klo + Qlo*Khi; f32 acc).
// P = exp(S) (bounded, no max-sub — validated rounds 4/5), stored bf16 to LDS in A-operand
// layout (C/D col=lane&15,row=quad*4+reg  ->  A[m=lane&15][k=quad*8+j] round-trip).
// PV: plain bf16 mfma, f32 accumulate. K/V staged per 64-key chunk in LDS; padded strides
// (40/72/72 elems) keep all ds_read_b128 at <=2-way bank aliasing (free).
#define KSTR 40
#define VSTR 72
#define PSTR 72

__global__ __launch_bounds__(256) void k_attn(const float* __restrict__ qkv,
    const int* __restrict__ sele, float* __restrict__ Oe, float* __restrict__ E)
{
    __shared__ __align__(16) unsigned short Khi[64 * KSTR];
    __shared__ __align__(16) unsigned short Klo[64 * KSTR];
    __shared__ __align__(16) unsigned short Vt[32 * VSTR];
    __shared__ __align__(16) unsigned short Pb[4][16 * PSTR];

    const int t = threadIdx.x;
    const int lane = t & 63;
    const int l = lane & 15;
    const int quad = lane >> 4;
    const int wv = __builtin_amdgcn_readfirstlane(t >> 6);
    const int qb = blockIdx.x;   // 64 q-blocks of 64
    const int h  = blockIdx.y;   // 4 heads
    const int ks = blockIdx.z;   // 4 key slots of 1024
    const int nk = sele[0];

    // Q A-fragment: row q = qb*64 + wv*16 + l; k-dim d = quad*8 + j. Scale then split hi/lo.
    short8 qhi, qlo;
    {
        const float* __restrict__ qr = qkv + (size_t)(qb * 64 + wv * 16 + l) * 384 + h * 32 + quad * 8;
        const float4 a = *(const float4*)qr;
        const float4 b = *(const float4*)(qr + 4);
        const float sc = 0.17677669529663687f;   // 1/sqrt(32)
        float v[8] = {a.x * sc, a.y * sc, a.z * sc, a.w * sc, b.x * sc, b.y * sc, b.z * sc, b.w * sc};
        #pragma unroll
        for (int j = 0; j < 8; ++j) {
            const unsigned short hb = f2bf(v[j]);
            qhi[j] = (short)hb;
            qlo[j] = (short)f2bf(v[j] - bf2f(hb));
        }
    }
    f32x4 accO0 = {0.f, 0.f, 0.f, 0.f};
    f32x4 accO1 = {0.f, 0.f, 0.f, 0.f};
    float e4[4] = {0.f, 0.f, 0.f, 0.f};

    for (int ch = 0; ch < 16; ++ch) {
        const int keybase = ks * 1024 + ch * 64;
        __syncthreads();                          // protect K/V LDS from previous chunk readers
        {   // cooperative stage: K split hi/lo [key][d], V transposed bf16 [d][key]
            const int kk = t >> 2;                // 0..63
            const int d0 = (t & 3) * 8;           // 0,8,16,24
            const float* __restrict__ kr = qkv + (size_t)(keybase + kk) * 384 + 128 + h * 32 + d0;
            const float4 ka = *(const float4*)kr;
            const float4 kb = *(const float4*)(kr + 4);
            const float* __restrict__ vr = qkv + (size_t)(keybase + kk) * 384 + 256 + h * 32 + d0;
            const float4 va = *(const float4*)vr;
            const float4 vb = *(const float4*)(vr + 4);
            const float kf[8] = {ka.x, ka.y, ka.z, ka.w, kb.x, kb.y, kb.z, kb.w};
            const float vf[8] = {va.x, va.y, va.z, va.w, vb.x, vb.y, vb.z, vb.w};
            unsigned hi[8], lo[8];
            #pragma unroll
            for (int j = 0; j < 8; ++j) {
                const unsigned short hb = f2bf(kf[j]);
                hi[j] = hb;
                lo[j] = f2bf(kf[j] - bf2f(hb));
            }
            unsigned* khw = (unsigned*)&Khi[kk * KSTR + d0];
            unsigned* klw = (unsigned*)&Klo[kk * KSTR + d0];
            #pragma unroll
            for (int j = 0; j < 4; ++j) {
                khw[j] = hi[2 * j] | (hi[2 * j + 1] << 16);
                klw[j] = lo[2 * j] | (lo[2 * j + 1] << 16);
            }
            #pragma unroll
            for (int j = 0; j < 8; ++j)
                Vt[(d0 + j) * VSTR + kk] = f2bf(vf[j]);
        }
        __syncthreads();
        unsigned short* __restrict__ Pw = Pb[wv];
        // QK^T: 4 S-tiles of 16 keys; exp; store P bf16 in A-layout
        #pragma unroll
        for (int tile = 0; tile < 4; ++tile) {
            const int kl = tile * 16 + l;
            const short8 kh = *(const short8*)&Khi[kl * KSTR + quad * 8];
            const short8 kw = *(const short8*)&Klo[kl * KSTR + quad * 8];
            f32x4 S = {0.f, 0.f, 0.f, 0.f};
            S = __builtin_amdgcn_mfma_f32_16x16x32_bf16(qhi, kh, S, 0, 0, 0);
            S = __builtin_amdgcn_mfma_f32_16x16x32_bf16(qhi, kw, S, 0, 0, 0);
            S = __builtin_amdgcn_mfma_f32_16x16x32_bf16(qlo, kh, S, 0, 0, 0);
            const int kg = keybase + kl;
            #pragma unroll
            for (int r = 0; r < 4; ++r) {
                const float p = (kg < nk) ? __expf(S[r]) : 0.f;
                e4[r] += p;
                Pw[(quad * 4 + r) * PSTR + tile * 16 + l] = f2bf(p);
            }
        }
        // PV: 2 k-steps of 32 keys x 2 d-tiles of 16
        #pragma unroll
        for (int step = 0; step < 2; ++step) {
            const short8 pa  = *(const short8*)&Pw[l * PSTR + step * 32 + quad * 8];
            const short8 vb0 = *(const short8*)&Vt[l * VSTR + step * 32 + quad * 8];
            const short8 vb1 = *(const short8*)&Vt[(16 + l) * VSTR + step * 32 + quad * 8];
            accO0 = __builtin_amdgcn_mfma_f32_16x16x32_bf16(pa, vb0, accO0, 0, 0, 0);
            accO1 = __builtin_amdgcn_mfma_f32_16x16x32_bf16(pa, vb1, accO1, 0, 0, 0);
        }
    }
    // E: reduce per-lane key-class partials over the 16 lanes of each quad
    #pragma unroll
    for (int r = 0; r < 4; ++r) {
        float e = e4[r];
        e += __shfl_xor(e, 1, 64);
        e += __shfl_xor(e, 2, 64);
        e += __shfl_xor(e, 4, 64);
        e += __shfl_xor(e, 8, 64);
        e4[r] = e;
    }
    const int qrow0 = qb * 64 + wv * 16;
    if (l == 0) {
        #pragma unroll
        for (int r = 0; r < 4; ++r)
            E[((size_t)ks * 4 + h) * 4096 + qrow0 + quad * 4 + r] = e4[r];
    }
    #pragma unroll
    for (int r = 0; r < 4; ++r) {
        const size_t row = qrow0 + quad * 4 + r;
        Oe[((size_t)ks * 4096 + row) * 128 + h * 32 + l]      = accO0[r];
        Oe[((size_t)ks * 4096 + row) * 128 + h * 32 + 16 + l] = accO1[r];
    }
}

// ---------------- K4: fold Oe/E + out-proj + residual + LN2 + FFN + residual + column-sum ----------------
__global__ __launch_bounds__(256) void k_ffn(const float* __restrict__ eig,
    const float* __restrict__ Oe, const float* __restrict__ E,
    const float* __restrict__ outW, const float* __restrict__ outb,
    const float* __restrict__ lg, const float* __restrict__ lb,
    const float* __restrict__ W1, const float* __restrict__ b1,
    const float* __restrict__ W2, const float* __restrict__ b2,
    const int* __restrict__ sele, float* __restrict__ xsum)
{
    __shared__ __align__(16) float sA[8][128];    // attention O rows, later gelu(h)
    __shared__ __align__(16) float x2[8][128];    // residual stream
    __shared__ __align__(16) float xn[8][128];    // LN2 output
    __shared__ float red1[8][32];
    __shared__ float red2[8][32];
    __shared__ float sEr[8][4];
    __shared__ float colsum[2][128];
    const int t = threadIdx.x;
    const int r0 = blockIdx.x * 8;
    const int r = t >> 5, l = t & 31;
    if (l < 4) {                                   // per-(row,head) reciprocal exp-sum
        float es = 0.f;
        #pragma unroll
        for (int ks = 0; ks < KSPLIT; ++ks)
            es += E[((size_t)ks * 4 + l) * 4096 + r0 + r];
        sEr[r][l] = 1.f / es;
    }
    __syncthreads();
    #pragma unroll
    for (int m = 0; m < 4; ++m) {                  // fold 4 slots -> O row
        const int col = l + 32 * m;
        float v = 0.f;
        #pragma unroll
        for (int ks = 0; ks < KSPLIT; ++ks)
            v += Oe[((size_t)ks * 4096 + r0 + r) * 128 + col];
        sA[r][col] = v * sEr[r][col >> 5];
    }
    __syncthreads();
    const int c = t & 127;
    const int rg = t >> 7;
    {   // out projection + residual
        float acc[4];
        const float bb = outb[c];
        #pragma unroll
        for (int i = 0; i < 4; ++i) acc[i] = bb;
        for (int k = 0; k < 128; k += 4) {
            const float w0 = outW[(k + 0) * 128 + c];
            const float w1 = outW[(k + 1) * 128 + c];
            const float w2 = outW[(k + 2) * 128 + c];
            const float w3 = outW[(k + 3) * 128 + c];
            #pragma unroll
            for (int i = 0; i < 4; ++i) {
                const float4 x = *(const float4*)&sA[rg + 2 * i][k];
                float a = acc[i];
                a = fmaf(x.x, w0, a);
                a = fmaf(x.y, w1, a);
                a = fmaf(x.z, w2, a);
                a = fmaf(x.w, w3, a);
                acc[i] = a;
            }
        }
        #pragma unroll
        for (int i = 0; i < 4; ++i)
            x2[rg + 2 * i][c] = eig[(r0 + rg + 2 * i) * 128 + c] + acc[i];
    }
    __syncthreads();
    {   // LN2
        float s = 0.f, ss = 0.f;
        float v[4];
        #pragma unroll
        for (int m = 0; m < 4; ++m) {
            const float x = x2[r][l + 32 * m];
            v[m] = x; s += x; ss += x * x;
        }
        red1[r][l] = s; red2[r][l] = ss;
        __syncthreads();
        for (int o = 16; o > 0; o >>= 1) {
            if (l < o) { red1[r][l] += red1[r][l + o]; red2[r][l] += red2[r][l + o]; }
            __syncthreads();
        }
        const float mean = red1[r][0] * (1.f / 128.f);
        const float var  = red2[r][0] * (1.f / 128.f) - mean * mean;
        const float inv  = 1.f / sqrtf(var + 1e-5f);
        #pragma unroll
        for (int m = 0; m < 4; ++m) {
            const int col = l + 32 * m;
            xn[r][col] = (v[m] - mean) * inv * lg[col] + lb[col];
        }
    }
    __syncthreads();
    {   // FFN1 + exact gelu -> sA
        float acc[4];
        const float bb = b1[c];
        #pragma unroll
        for (int i = 0; i < 4; ++i) acc[i] = bb;
        for (int k = 0; k < 128; k += 4) {
            const float w0 = W1[(k + 0) * 128 + c];
            const float w1 = W1[(k + 1) * 128 + c];
            const float w2 = W1[(k + 2) * 128 + c];
            const float w3 = W1[(k + 3) * 128 + c];
            #pragma unroll
            for (int i = 0; i < 4; ++i) {
                const float4 x = *(const float4*)&xn[rg + 2 * i][k];
                float a = acc[i];
                a = fmaf(x.x, w0, a);
                a = fmaf(x.y, w1, a);
                a = fmaf(x.z, w2, a);
                a = fmaf(x.w, w3, a);
                acc[i] = a;
            }
        }
        __syncthreads();
        #pragma unroll
        for (int i = 0; i < 4; ++i) {
            const float x = acc[i];
            sA[rg + 2 * i][c] = 0.5f * x * (1.f + erff(x * 0.70710678118654752f));
        }
    }
    __syncthreads();
    {   // FFN2 + residual + masked column sum
        float acc[4];
        const float bb = b2[c];
        #pragma unroll
        for (int i = 0; i < 4; ++i) acc[i] = bb;
        for (int k = 0; k < 128; k += 4) {
            const float w0 = W2[(k + 0) * 128 + c];
            const float w1 = W2[(k + 1) * 128 + c];
            const float w2 = W2[(k + 2) * 128 + c];
            const float w3 = W2[(k + 3) * 128 + c];
            #pragma unroll
            for (int i = 0; i < 4; ++i) {
                const float4 x = *(const float4*)&sA[rg + 2 * i][k];
                float a = acc[i];
                a = fmaf(x.x, w0, a);
                a = fmaf(x.y, w1, a);
                a = fmaf(x.z, w2, a);
                a = fmaf(x.w, w3, a);
                acc[i] = a;
            }
        }
        const int nsel = sele[0];
        float local = 0.f;
        #pragma unroll
        for (int i = 0; i < 4; ++i) {
            const float ef = x2[rg + 2 * i][c] + acc[i];
            if (r0 + rg + 2 * i < nsel) local += ef;
        }
        colsum[rg][c] = local;
    }
    __syncthreads();
    if (rg == 0) atomicAdd(&xsum[c], colsum[0][c] + colsum[1][c]);
}

// ---------------- K5: pooled coefficients ----------------
__global__ __launch_bounds__(128) void k_coef(const float* __restrict__ xsum,
    const float* __restrict__ dscW, const float* __restrict__ dscb,
    const float* __restrict__ dwvW, const float* __restrict__ dwvb,
    const float* __restrict__ dssW, const float* __restrict__ dssb,
    const int* __restrict__ len, const int* __restrict__ sele,
    float* __restrict__ coef)
{
    __shared__ float xs[128];
    __shared__ float csc[50], cwv[50];
    __shared__ float s2[2];
    const int t = threadIdx.x;
    xs[t] = xsum[t];
    __syncthreads();
    const float invl = 1.f / ((float)len[0] + 1e-8f);
    const float ns = (float)sele[0];
    if (t < 50) {
        float a = ns * dscb[t];
        for (int k = 0; k < 128; ++k) a = fmaf(xs[k], dscW[k * 50 + t], a);
        a *= invl;
        csc[t] = 1.f / (1.f + expf(-a));
    } else if (t >= 64 && t < 114) {
        const int j = t - 64;
        float a = ns * dwvb[j];
        for (int k = 0; k < 128; ++k) a = fmaf(xs[k], dwvW[k * 50 + j], a);
        a *= invl;
        cwv[j] = 1.f / (1.f + expf(-a));
    } else if (t >= 114 && t < 118) {
        const int j = t - 114;
        float a = ns * dssb[j];
        for (int k = 0; k < 128; ++k) a = fmaf(xs[k], dssW[k * 4 + j], a);
        a *= invl;
        coef[100 + j] = (1.f / (1.f + expf(-a))) * 5.0f;  // THRE
    }
    __syncthreads();
    if (t == 0) { float s = 0.f; for (int i2 = 0; i2 < 50; ++i2) s += csc[i2]; s2[0] = s; }
    if (t == 1) { float s = 0.f; for (int i2 = 0; i2 < 50; ++i2) s += cwv[i2]; s2[1] = s; }
    __syncthreads();
    if (t < 50) {
        coef[t]      = csc[t] / (s2[0] + 1e-8f);
        coef[50 + t] = cwv[t] / (s2[1] + 1e-8f);
    }
}

// ---------------- K6: Chebyshev bases + combine + normalize ----------------
__global__ __launch_bounds__(256) void k_out(const float* __restrict__ eve,
    const float* __restrict__ coef, float* __restrict__ out)
{
    __shared__ float csc[50], cwv[50], cs[4];
    const int t = threadIdx.x;
    if (t < 50) csc[t] = coef[t];
    else if (t < 100) cwv[t - 50] = coef[t];
    else if (t < 104) cs[t - 100] = coef[t];
    __syncthreads();
    const int s = blockIdx.x * 256 + t;
    const float e = eve[s];
    float vals[5];
    {   // scaling: [T1, T3, ..., T99](e-1); 0.5*(1-T)
        const float y = e - 1.f;
        float te = 1.f, to = y;
        float a = csc[0] * (0.5f * (1.f - to));
        const float y2 = 2.f * y;
        for (int i = 1; i < 50; ++i) {
            te = fmaf(y2, to, -te);
            to = fmaf(y2, te, -to);
            a = fmaf(csc[i], 0.5f * (1.f - to), a);
        }
        vals[0] = a;
    }
    #pragma unroll
    for (int j = 0; j < 4; ++j) {  // wavelet: [T0, T2, ..., T98](fsw-1)
        float f = e * cs[j];
        if (f > 2.f) f = 0.f;
        const float y = f - 1.f;
        float te = 1.f, to = y;
        float a = cwv[0] * (0.5f * (1.f - te));
        const float y2 = 2.f * y;
        for (int i = 1; i < 50; ++i) {
            te = fmaf(y2, to, -te);
            to = fmaf(y2, te, -to);
            a = fmaf(cwv[i], 0.5f * (1.f - te), a);
        }
        vals[1 + j] = a;
    }
    float n2 = 0.f;
    #pragma unroll
    for (int k = 0; k < 5; ++k) n2 += vals[k] * vals[k];
    const float invn = 1.f / (sqrtf(n2) + 1e-8f);
    #pragma unroll
    for (int k = 0; k < 5; ++k) out[s * 5 + k] = vals[k] * invn;
}

extern "C" void kernel_launch(void* const* d_in, const int* in_sizes, int n_in,
                              void* d_out, int out_size, void* d_ws, size_t ws_size,
                              hipStream_t stream) {
    const float* eve  = (const float*)d_in[0];
    const int*   len  = (const int*)d_in[1];
    const int*   sele = (const int*)d_in[2];
    const float* eigW = (const float*)d_in[3];
    const float* eigB = (const float*)d_in[4];
    const float* mlg  = (const float*)d_in[5];
    const float* mlb  = (const float*)d_in[6];
    const float* inW  = (const float*)d_in[7];
    const float* inb  = (const float*)d_in[8];
    const float* outW = (const float*)d_in[9];
    const float* outb = (const float*)d_in[10];
    const float* flg  = (const float*)d_in[11];
    const float* flb  = (const float*)d_in[12];
    const float* W1   = (const float*)d_in[13];
    const float* b1   = (const float*)d_in[14];
    const float* W2   = (const float*)d_in[15];
    const float* b2   = (const float*)d_in[16];
    const float* dscW = (const float*)d_in[17];
    const float* dscb = (const float*)d_in[18];
    const float* dwvW = (const float*)d_in[19];
    const float* dwvb = (const float*)d_in[20];
    const float* dssW = (const float*)d_in[21];
    const float* dssb = (const float*)d_in[22];

    float* ws   = (float*)d_ws;
    float* eig  = ws;
    float* qkv  = ws + 524288;
    float* Oe   = ws + 2097152;
    float* E    = ws + 4194304;
    float* xsum = ws + 4259840;
    float* coef = ws + 4259968;
    float* out  = (float*)d_out;

    hipMemsetAsync(xsum, 0, 128 * sizeof(float), stream);
    k_eig <<<512, 256, 0, stream>>>(eve, eigW, eigB, eig);
    k_qkv <<<512, 256, 0, stream>>>(eig, mlg, mlb, inW, inb, qkv);
    k_attn<<<dim3(64, 4, KSPLIT), 256, 0, stream>>>(qkv, sele, Oe, E);
    k_ffn <<<512, 256, 0, stream>>>(eig, Oe, E, outW, outb, flg, flb, W1, b1, W2, b2, sele, xsum);
    k_coef<<<1, 128, 0, stream>>>(xsum, dscW, dscb, dwvW, dwvb, dssW, dssb, len, sele, coef);
    k_out <<<16, 256, 0, stream>>>(eve, coef, out);
}

// Round 7
// 224.663 us; speedup vs baseline: 1.9380x; 1.0358x over previous
//
#include <hip/hip_runtime.h>
#include <math.h>

// Problem constants (B=1): S=4096, D=128, NHEADS=4, hd=32, N_COE=50, N_SCALES=4, THRE=5
//
// ws layout (floats):
//   eig  @ 0        (4096*128   = 524288)
//   qkv  @ 524288   (4096*384   = 1572864)
//   Oe   @ 2097152  (4*4096*128 = 2097152)   exp-weighted V partials (f32 MFMA accum), 4 key slots
//   E    @ 4194304  (4*4*4096   = 65536)     exp sums, [ks][h][q]
//   xsum @ 4259840  (128)
//   coef @ 4259968  (104)
// total ~17 MB

#define KSPLIT 4

typedef __attribute__((ext_vector_type(8))) short short8;   // 8 bf16 (4 VGPRs)
typedef __attribute__((ext_vector_type(4))) float f32x4;

__device__ inline unsigned short f2bf(float x) {            // RNE f32->bf16 bits
    unsigned u = __float_as_uint(x);
    return (unsigned short)((u + 0x7FFFu + ((u >> 16) & 1u)) >> 16);
}
__device__ inline float bf2f(unsigned short h) { return __uint_as_float(((unsigned)h) << 16); }

// ---------------- K1: sine encoding + eig = eeig @ W + b (8 rows/block, 512 blocks) ----------------
__global__ __launch_bounds__(256) void k_eig(const float* __restrict__ eve,
    const float* __restrict__ W, const float* __restrict__ bias,
    float* __restrict__ eig)
{
    __shared__ __align__(16) float se[8][132];    // [0..63]=sin, [64..127]=cos, [128]=e
    const int t = threadIdx.x;
    const int r0 = blockIdx.x * 8;
    {
        const int r = t >> 5, l = t & 31;
        const float e = eve[r0 + r];
        if (l == 0) se[r][128] = e;
        const float e100 = e * 100.0f;
        #pragma unroll
        for (int jj = 0; jj < 2; ++jj) {
            const int j = l * 2 + jj;             // 0..63
            const float div = expf(-0.07195578415606394f * (float)(2 * j));
            const float pe = e100 * div;
            se[r][j]      = sinf(pe);
            se[r][64 + j] = cosf(pe);
        }
    }
    __syncthreads();
    const int c = t & 127;
    const int rg = t >> 7;                        // 0..1; rows rg+2i, i<4
    float acc[4];
    {
        const float w0 = W[c];                    // W row 0 pairs with raw e
        #pragma unroll
        for (int i = 0; i < 4; ++i) acc[i] = se[rg + 2 * i][128] * w0;
    }
    #pragma unroll 1                              // bound the hoist window (VGPR/spill control)
    for (int k = 0; k < 128; k += 4) {            // se[.][k] pairs W[k+1]
        const float w0 = W[(k + 1) * 128 + c];
        const float w1 = W[(k + 2) * 128 + c];
        const float w2 = W[(k + 3) * 128 + c];
        const float w3 = W[(k + 4) * 128 + c];
        #pragma unroll
        for (int i = 0; i < 4; ++i) {
            const float4 x = *(const float4*)&se[rg + 2 * i][k];
            float a = acc[i];
            a = fmaf(x.x, w0, a);
            a = fmaf(x.y, w1, a);
            a = fmaf(x.z, w2, a);
            a = fmaf(x.w, w3, a);
            acc[i] = a;
        }
    }
    const float bb = bias[c];
    #pragma unroll
    for (int i = 0; i < 4; ++i) eig[(r0 + rg + 2 * i) * 128 + c] = acc[i] + bb;
}

// ---------------- K2: LN1 + qkv = ln(eig) @ in_W + in_b (8 rows/block, 512 blocks) ----------------
__global__ __launch_bounds__(256) void k_qkv(const float* __restrict__ eig,
    const float* __restrict__ g, const float* __restrict__ b,
    const float* __restrict__ inW, const float* __restrict__ inb,
    float* __restrict__ qkv)
{
    __shared__ __align__(16) float xn[8][128];
    __shared__ float red1[8][32];
    __shared__ float red2[8][32];
    const int t = threadIdx.x;
    const int r0 = blockIdx.x * 8;
    const int r = t >> 5, l = t & 31;
    float v[4];
    {
        float s = 0.f, ss = 0.f;
        #pragma unroll
        for (int m = 0; m < 4; ++m) {
            const float x = eig[(r0 + r) * 128 + l + 32 * m];
            v[m] = x; s += x; ss += x * x;
        }
        red1[r][l] = s; red2[r][l] = ss;
    }
    __syncthreads();
    for (int o = 16; o > 0; o >>= 1) {
        if (l < o) { red1[r][l] += red1[r][l + o]; red2[r][l] += red2[r][l + o]; }
        __syncthreads();
    }
    {
        const float mean = red1[r][0] * (1.f / 128.f);
        const float var  = red2[r][0] * (1.f / 128.f) - mean * mean;
        const float inv  = 1.f / sqrtf(var + 1e-5f);
        #pragma unroll
        for (int m = 0; m < 4; ++m) {
            const int col = l + 32 * m;
            xn[r][col] = (v[m] - mean) * inv * g[col] + b[col];
        }
    }
    __syncthreads();
    const int cbase = t & 127;
    const int rg = t >> 7;
    float acc[3][4];
    #pragma unroll
    for (int p = 0; p < 3; ++p) {
        const float bb = inb[p * 128 + cbase];
        #pragma unroll
        for (int i = 0; i < 4; ++i) acc[p][i] = bb;
    }
    #pragma unroll 1                              // bound the hoist window (VGPR/spill control)
    for (int k = 0; k < 128; k += 4) {
        float4 xv[4];
        #pragma unroll
        for (int i = 0; i < 4; ++i) xv[i] = *(const float4*)&xn[rg + 2 * i][k];
        #pragma unroll
        for (int p = 0; p < 3; ++p) {
            const int c = p * 128 + cbase;
            const float w0 = inW[(k + 0) * 384 + c];
            const float w1 = inW[(k + 1) * 384 + c];
            const float w2 = inW[(k + 2) * 384 + c];
            const float w3 = inW[(k + 3) * 384 + c];
            #pragma unroll
            for (int i = 0; i < 4; ++i) {
                float a = acc[p][i];
                a = fmaf(xv[i].x, w0, a);
                a = fmaf(xv[i].y, w1, a);
                a = fmaf(xv[i].z, w2, a);
                a = fmaf(xv[i].w, w3, a);
                acc[p][i] = a;
            }
        }
    }
    #pragma unroll
    for (int p = 0; p < 3; ++p)
        #pragma unroll
        for (int i = 0; i < 4; ++i)
            qkv[(r0 + rg + 2 * i) * 384 + p * 128 + cbase] = acc[p][i];
}

// ---------------- K3: MFMA flash attention (no-max linear partials) ----------------
// Block = (qblock of 64 queries, head, key-slot of 1024). 4 waves = 4 q-subtiles of 16.
// QK^T: mfma_f32_16x16x32_bf16 with split-2 bf16 (S = Qhi*Khi + Qhi*Klo + Qlo*Khi; f32 acc).
// P = exp(S) (bounded, no max-sub — validated rounds 4/5), stored bf16 to LDS in A-operand
// layout. PV: plain bf16 mfma, f32 accumulate. K/V staged per 64-key chunk in LDS; padded
// strides (40/72/72 elems) keep all ds_read_b128 at <=2-way bank aliasing (free).
#define KSTR 40
#define VSTR 72
#define PSTR 72

__global__ __launch_bounds__(256) void k_attn(const float* __restrict__ qkv,
    const int* __restrict__ sele, float* __restrict__ Oe, float* __restrict__ E)
{
    __shared__ __align__(16) unsigned short Khi[64 * KSTR];
    __shared__ __align__(16) unsigned short Klo[64 * KSTR];
    __shared__ __align__(16) unsigned short Vt[32 * VSTR];
    __shared__ __align__(16) unsigned short Pb[4][16 * PSTR];

    const int t = threadIdx.x;
    const int lane = t & 63;
    const int l = lane & 15;
    const int quad = lane >> 4;
    const int wv = __builtin_amdgcn_readfirstlane(t >> 6);
    const int qb = blockIdx.x;   // 64 q-blocks of 64
    const int h  = blockIdx.y;   // 4 heads
    const int ks = blockIdx.z;   // 4 key slots of 1024
    const int nk = sele[0];

    // Q A-fragment: row q = qb*64 + wv*16 + l; k-dim d = quad*8 + j. Scale then split hi/lo.
    short8 qhi, qlo;
    {
        const float* __restrict__ qr = qkv + (size_t)(qb * 64 + wv * 16 + l) * 384 + h * 32 + quad * 8;
        const float4 a = *(const float4*)qr;
        const float4 b = *(const float4*)(qr + 4);
        const float sc = 0.17677669529663687f;   // 1/sqrt(32)
        float v[8] = {a.x * sc, a.y * sc, a.z * sc, a.w * sc, b.x * sc, b.y * sc, b.z * sc, b.w * sc};
        #pragma unroll
        for (int j = 0; j < 8; ++j) {
            const unsigned short hb = f2bf(v[j]);
            qhi[j] = (short)hb;
            qlo[j] = (short)f2bf(v[j] - bf2f(hb));
        }
    }
    f32x4 accO0 = {0.f, 0.f, 0.f, 0.f};
    f32x4 accO1 = {0.f, 0.f, 0.f, 0.f};
    float e4[4] = {0.f, 0.f, 0.f, 0.f};

    for (int ch = 0; ch < 16; ++ch) {
        const int keybase = ks * 1024 + ch * 64;
        __syncthreads();                          // protect K/V LDS from previous chunk readers
        {   // cooperative stage: K split hi/lo [key][d], V transposed bf16 [d][key]
            const int kk = t >> 2;                // 0..63
            const int d0 = (t & 3) * 8;           // 0,8,16,24
            const float* __restrict__ kr = qkv + (size_t)(keybase + kk) * 384 + 128 + h * 32 + d0;
            const float4 ka = *(const float4*)kr;
            const float4 kb = *(const float4*)(kr + 4);
            const float* __restrict__ vr = qkv + (size_t)(keybase + kk) * 384 + 256 + h * 32 + d0;
            const float4 va = *(const float4*)vr;
            const float4 vb = *(const float4*)(vr + 4);
            const float kf[8] = {ka.x, ka.y, ka.z, ka.w, kb.x, kb.y, kb.z, kb.w};
            const float vf[8] = {va.x, va.y, va.z, va.w, vb.x, vb.y, vb.z, vb.w};
            unsigned hi[8], lo[8];
            #pragma unroll
            for (int j = 0; j < 8; ++j) {
                const unsigned short hb = f2bf(kf[j]);
                hi[j] = hb;
                lo[j] = f2bf(kf[j] - bf2f(hb));
            }
            unsigned* khw = (unsigned*)&Khi[kk * KSTR + d0];
            unsigned* klw = (unsigned*)&Klo[kk * KSTR + d0];
            #pragma unroll
            for (int j = 0; j < 4; ++j) {
                khw[j] = hi[2 * j] | (hi[2 * j + 1] << 16);
                klw[j] = lo[2 * j] | (lo[2 * j + 1] << 16);
            }
            #pragma unroll
            for (int j = 0; j < 8; ++j)
                Vt[(d0 + j) * VSTR + kk] = f2bf(vf[j]);
        }
        __syncthreads();
        unsigned short* __restrict__ Pw = Pb[wv];
        // QK^T: 4 S-tiles of 16 keys; exp; store P bf16 in A-layout
        #pragma unroll
        for (int tile = 0; tile < 4; ++tile) {
            const int kl = tile * 16 + l;
            const short8 kh = *(const short8*)&Khi[kl * KSTR + quad * 8];
            const short8 kw = *(const short8*)&Klo[kl * KSTR + quad * 8];
            f32x4 S = {0.f, 0.f, 0.f, 0.f};
            S = __builtin_amdgcn_mfma_f32_16x16x32_bf16(qhi, kh, S, 0, 0, 0);
            S = __builtin_amdgcn_mfma_f32_16x16x32_bf16(qhi, kw, S, 0, 0, 0);
            S = __builtin_amdgcn_mfma_f32_16x16x32_bf16(qlo, kh, S, 0, 0, 0);
            const int kg = keybase + kl;
            #pragma unroll
            for (int r = 0; r < 4; ++r) {
                const float p = (kg < nk) ? __expf(S[r]) : 0.f;
                e4[r] += p;
                Pw[(quad * 4 + r) * PSTR + tile * 16 + l] = f2bf(p);
            }
        }
        // PV: 2 k-steps of 32 keys x 2 d-tiles of 16
        #pragma unroll
        for (int step = 0; step < 2; ++step) {
            const short8 pa  = *(const short8*)&Pw[l * PSTR + step * 32 + quad * 8];
            const short8 vb0 = *(const short8*)&Vt[l * VSTR + step * 32 + quad * 8];
            const short8 vb1 = *(const short8*)&Vt[(16 + l) * VSTR + step * 32 + quad * 8];
            accO0 = __builtin_amdgcn_mfma_f32_16x16x32_bf16(pa, vb0, accO0, 0, 0, 0);
            accO1 = __builtin_amdgcn_mfma_f32_16x16x32_bf16(pa, vb1, accO1, 0, 0, 0);
        }
    }
    // E: reduce per-lane key-class partials over the 16 lanes of each quad
    #pragma unroll
    for (int r = 0; r < 4; ++r) {
        float e = e4[r];
        e += __shfl_xor(e, 1, 64);
        e += __shfl_xor(e, 2, 64);
        e += __shfl_xor(e, 4, 64);
        e += __shfl_xor(e, 8, 64);
        e4[r] = e;
    }
    const int qrow0 = qb * 64 + wv * 16;
    if (l == 0) {
        #pragma unroll
        for (int r = 0; r < 4; ++r)
            E[((size_t)ks * 4 + h) * 4096 + qrow0 + quad * 4 + r] = e4[r];
    }
    #pragma unroll
    for (int r = 0; r < 4; ++r) {
        const size_t row = qrow0 + quad * 4 + r;
        Oe[((size_t)ks * 4096 + row) * 128 + h * 32 + l]      = accO0[r];
        Oe[((size_t)ks * 4096 + row) * 128 + h * 32 + 16 + l] = accO1[r];
    }
}

// ---------------- K4: fold Oe/E + out-proj + residual + LN2 + FFN + residual + column-sum ----------------
__global__ __launch_bounds__(256) void k_ffn(const float* __restrict__ eig,
    const float* __restrict__ Oe, const float* __restrict__ E,
    const float* __restrict__ outW, const float* __restrict__ outb,
    const float* __restrict__ lg, const float* __restrict__ lb,
    const float* __restrict__ W1, const float* __restrict__ b1,
    const float* __restrict__ W2, const float* __restrict__ b2,
    const int* __restrict__ sele, float* __restrict__ xsum)
{
    __shared__ __align__(16) float sA[8][128];    // attention O rows, later gelu(h)
    __shared__ __align__(16) float x2[8][128];    // residual stream
    __shared__ __align__(16) float xn[8][128];    // LN2 output
    __shared__ float red1[8][32];
    __shared__ float red2[8][32];
    __shared__ float sEr[8][4];
    __shared__ float colsum[2][128];
    const int t = threadIdx.x;
    const int r0 = blockIdx.x * 8;
    const int r = t >> 5, l = t & 31;
    if (l < 4) {                                   // per-(row,head) reciprocal exp-sum
        float es = 0.f;
        #pragma unroll
        for (int ks = 0; ks < KSPLIT; ++ks)
            es += E[((size_t)ks * 4 + l) * 4096 + r0 + r];
        sEr[r][l] = 1.f / es;
    }
    __syncthreads();
    #pragma unroll
    for (int m = 0; m < 4; ++m) {                  // fold 4 slots -> O row
        const int col = l + 32 * m;
        float v = 0.f;
        #pragma unroll
        for (int ks = 0; ks < KSPLIT; ++ks)
            v += Oe[((size_t)ks * 4096 + r0 + r) * 128 + col];
        sA[r][col] = v * sEr[r][col >> 5];
    }
    __syncthreads();
    const int c = t & 127;
    const int rg = t >> 7;
    {   // out projection + residual
        float acc[4];
        const float bb = outb[c];
        #pragma unroll
        for (int i = 0; i < 4; ++i) acc[i] = bb;
        #pragma unroll 1                           // bound the hoist window (VGPR/spill control)
        for (int k = 0; k < 128; k += 4) {
            const float w0 = outW[(k + 0) * 128 + c];
            const float w1 = outW[(k + 1) * 128 + c];
            const float w2 = outW[(k + 2) * 128 + c];
            const float w3 = outW[(k + 3) * 128 + c];
            #pragma unroll
            for (int i = 0; i < 4; ++i) {
                const float4 x = *(const float4*)&sA[rg + 2 * i][k];
                float a = acc[i];
                a = fmaf(x.x, w0, a);
                a = fmaf(x.y, w1, a);
                a = fmaf(x.z, w2, a);
                a = fmaf(x.w, w3, a);
                acc[i] = a;
            }
        }
        #pragma unroll
        for (int i = 0; i < 4; ++i)
            x2[rg + 2 * i][c] = eig[(r0 + rg + 2 * i) * 128 + c] + acc[i];
    }
    __syncthreads();
    {   // LN2
        float s = 0.f, ss = 0.f;
        float v[4];
        #pragma unroll
        for (int m = 0; m < 4; ++m) {
            const float x = x2[r][l + 32 * m];
            v[m] = x; s += x; ss += x * x;
        }
        red1[r][l] = s; red2[r][l] = ss;
        __syncthreads();
        for (int o = 16; o > 0; o >>= 1) {
            if (l < o) { red1[r][l] += red1[r][l + o]; red2[r][l] += red2[r][l + o]; }
            __syncthreads();
        }
        const float mean = red1[r][0] * (1.f / 128.f);
        const float var  = red2[r][0] * (1.f / 128.f) - mean * mean;
        const float inv  = 1.f / sqrtf(var + 1e-5f);
        #pragma unroll
        for (int m = 0; m < 4; ++m) {
            const int col = l + 32 * m;
            xn[r][col] = (v[m] - mean) * inv * lg[col] + lb[col];
        }
    }
    __syncthreads();
    {   // FFN1 + exact gelu -> sA
        float acc[4];
        const float bb = b1[c];
        #pragma unroll
        for (int i = 0; i < 4; ++i) acc[i] = bb;
        #pragma unroll 1                           // bound the hoist window (VGPR/spill control)
        for (int k = 0; k < 128; k += 4) {
            const float w0 = W1[(k + 0) * 128 + c];
            const float w1 = W1[(k + 1) * 128 + c];
            const float w2 = W1[(k + 2) * 128 + c];
            const float w3 = W1[(k + 3) * 128 + c];
            #pragma unroll
            for (int i = 0; i < 4; ++i) {
                const float4 x = *(const float4*)&xn[rg + 2 * i][k];
                float a = acc[i];
                a = fmaf(x.x, w0, a);
                a = fmaf(x.y, w1, a);
                a = fmaf(x.z, w2, a);
                a = fmaf(x.w, w3, a);
                acc[i] = a;
            }
        }
        __syncthreads();
        #pragma unroll
        for (int i = 0; i < 4; ++i) {
            const float x = acc[i];
            sA[rg + 2 * i][c] = 0.5f * x * (1.f + erff(x * 0.70710678118654752f));
        }
    }
    __syncthreads();
    {   // FFN2 + residual + masked column sum
        float acc[4];
        const float bb = b2[c];
        #pragma unroll
        for (int i = 0; i < 4; ++i) acc[i] = bb;
        #pragma unroll 1                           // bound the hoist window (VGPR/spill control)
        for (int k = 0; k < 128; k += 4) {
            const float w0 = W2[(k + 0) * 128 + c];
            const float w1 = W2[(k + 1) * 128 + c];
            const float w2 = W2[(k + 2) * 128 + c];
            const float w3 = W2[(k + 3) * 128 + c];
            #pragma unroll
            for (int i = 0; i < 4; ++i) {
                const float4 x = *(const float4*)&sA[rg + 2 * i][k];
                float a = acc[i];
                a = fmaf(x.x, w0, a);
                a = fmaf(x.y, w1, a);
                a = fmaf(x.z, w2, a);
                a = fmaf(x.w, w3, a);
                acc[i] = a;
            }
        }
        const int nsel = sele[0];
        float local = 0.f;
        #pragma unroll
        for (int i = 0; i < 4; ++i) {
            const float ef = x2[rg + 2 * i][c] + acc[i];
            if (r0 + rg + 2 * i < nsel) local += ef;
        }
        colsum[rg][c] = local;
    }
    __syncthreads();
    if (rg == 0) atomicAdd(&xsum[c], colsum[0][c] + colsum[1][c]);
}

// ---------------- K5: pooled coefficients ----------------
__global__ __launch_bounds__(128) void k_coef(const float* __restrict__ xsum,
    const float* __restrict__ dscW, const float* __restrict__ dscb,
    const float* __restrict__ dwvW, const float* __restrict__ dwvb,
    const float* __restrict__ dssW, const float* __restrict__ dssb,
    const int* __restrict__ len, const int* __restrict__ sele,
    float* __restrict__ coef)
{
    __shared__ float xs[128];
    __shared__ float csc[50], cwv[50];
    __shared__ float s2[2];
    const int t = threadIdx.x;
    xs[t] = xsum[t];
    __syncthreads();
    const float invl = 1.f / ((float)len[0] + 1e-8f);
    const float ns = (float)sele[0];
    if (t < 50) {
        float a = ns * dscb[t];
        for (int k = 0; k < 128; ++k) a = fmaf(xs[k], dscW[k * 50 + t], a);
        a *= invl;
        csc[t] = 1.f / (1.f + expf(-a));
    } else if (t >= 64 && t < 114) {
        const int j = t - 64;
        float a = ns * dwvb[j];
        for (int k = 0; k < 128; ++k) a = fmaf(xs[k], dwvW[k * 50 + j], a);
        a *= invl;
        cwv[j] = 1.f / (1.f + expf(-a));
    } else if (t >= 114 && t < 118) {
        const int j = t - 114;
        float a = ns * dssb[j];
        for (int k = 0; k < 128; ++k) a = fmaf(xs[k], dssW[k * 4 + j], a);
        a *= invl;
        coef[100 + j] = (1.f / (1.f + expf(-a))) * 5.0f;  // THRE
    }
    __syncthreads();
    if (t == 0) { float s = 0.f; for (int i2 = 0; i2 < 50; ++i2) s += csc[i2]; s2[0] = s; }
    if (t == 1) { float s = 0.f; for (int i2 = 0; i2 < 50; ++i2) s += cwv[i2]; s2[1] = s; }
    __syncthreads();
    if (t < 50) {
        coef[t]      = csc[t] / (s2[0] + 1e-8f);
        coef[50 + t] = cwv[t] / (s2[1] + 1e-8f);
    }
}

// ---------------- K6: Chebyshev bases + combine + normalize ----------------
__global__ __launch_bounds__(256) void k_out(const float* __restrict__ eve,
    const float* __restrict__ coef, float* __restrict__ out)
{
    __shared__ float csc[50], cwv[50], cs[4];
    const int t = threadIdx.x;
    if (t < 50) csc[t] = coef[t];
    else if (t < 100) cwv[t - 50] = coef[t];
    else if (t < 104) cs[t - 100] = coef[t];
    __syncthreads();
    const int s = blockIdx.x * 256 + t;
    const float e = eve[s];
    float vals[5];
    {   // scaling: [T1, T3, ..., T99](e-1); 0.5*(1-T)
        const float y = e - 1.f;
        float te = 1.f, to = y;
        float a = csc[0] * (0.5f * (1.f - to));
        const float y2 = 2.f * y;
        for (int i = 1; i < 50; ++i) {
            te = fmaf(y2, to, -te);
            to = fmaf(y2, te, -to);
            a = fmaf(csc[i], 0.5f * (1.f - to), a);
        }
        vals[0] = a;
    }
    #pragma unroll
    for (int j = 0; j < 4; ++j) {  // wavelet: [T0, T2, ..., T98](fsw-1)
        float f = e * cs[j];
        if (f > 2.f) f = 0.f;
        const float y = f - 1.f;
        float te = 1.f, to = y;
        float a = cwv[0] * (0.5f * (1.f - te));
        const float y2 = 2.f * y;
        for (int i = 1; i < 50; ++i) {
            te = fmaf(y2, to, -te);
            to = fmaf(y2, te, -to);
            a = fmaf(cwv[i], 0.5f * (1.f - te), a);
        }
        vals[1 + j] = a;
    }
    float n2 = 0.f;
    #pragma unroll
    for (int k = 0; k < 5; ++k) n2 += vals[k] * vals[k];
    const float invn = 1.f / (sqrtf(n2) + 1e-8f);
    #pragma unroll
    for (int k = 0; k < 5; ++k) out[s * 5 + k] = vals[k] * invn;
}

extern "C" void kernel_launch(void* const* d_in, const int* in_sizes, int n_in,
                              void* d_out, int out_size, void* d_ws, size_t ws_size,
                              hipStream_t stream) {
    const float* eve  = (const float*)d_in[0];
    const int*   len  = (const int*)d_in[1];
    const int*   sele = (const int*)d_in[2];
    const float* eigW = (const float*)d_in[3];
    const float* eigB = (const float*)d_in[4];
    const float* mlg  = (const float*)d_in[5];
    const float* mlb  = (const float*)d_in[6];
    const float* inW  = (const float*)d_in[7];
    const float* inb  = (const float*)d_in[8];
    const float* outW = (const float*)d_in[9];
    const float* outb = (const float*)d_in[10];
    const float* flg  = (const float*)d_in[11];
    const float* flb  = (const float*)d_in[12];
    const float* W1   = (const float*)d_in[13];
    const float* b1   = (const float*)d_in[14];
    const float* W2   = (const float*)d_in[15];
    const float* b2   = (const float*)d_in[16];
    const float* dscW = (const float*)d_in[17];
    const float* dscb = (const float*)d_in[18];
    const float* dwvW = (const float*)d_in[19];
    const float* dwvb = (const float*)d_in[20];
    const float* dssW = (const float*)d_in[21];
    const float* dssb = (const float*)d_in[22];

    float* ws   = (float*)d_ws;
    float* eig  = ws;
    float* qkv  = ws + 524288;
    float* Oe   = ws + 2097152;
    float* E    = ws + 4194304;
    float* xsum = ws + 4259840;
    float* coef = ws + 4259968;
    float* out  = (float*)d_out;

    hipMemsetAsync(xsum, 0, 128 * sizeof(float), stream);
    k_eig <<<512, 256, 0, stream>>>(eve, eigW, eigB, eig);
    k_qkv <<<512, 256, 0, stream>>>(eig, mlg, mlb, inW, inb, qkv);
    k_attn<<<dim3(64, 4, KSPLIT), 256, 0, stream>>>(qkv, sele, Oe, E);
    k_ffn <<<512, 256, 0, stream>>>(eig, Oe, E, outW, outb, flg, flb, W1, b1, W2, b2, sele, xsum);
    k_coef<<<1, 128, 0, stream>>>(xsum, dscW, dscb, dwvW, dwvb, dssW, dssb, len, sele, coef);
    k_out <<<16, 256, 0, stream>>>(eve, coef, out);
}

// Round 8
// 213.084 us; speedup vs baseline: 2.0433x; 1.0543x over previous
//
#include <hip/hip_runtime.h>
#include <math.h>

// Problem constants (B=1): S=4096, D=128, NHEADS=4, hd=32, N_COE=50, N_SCALES=4, THRE=5
//
// ws layout (floats):
//   eig   @ 0        (524288)
//   qkv   @ 524288   (1572864; only Q panel [.,0..127] written/used in f32)
//   Oe    @ 2097152  (4*4096*128 = 2097152)
//   E     @ 4194304  (4*4*4096 = 65536)
//   xsum  @ 4259840  (128)
//   coef  @ 4259968  (104; pad to 384)
//   Khi_g @ 4260352  (262144 floats = 524288 ushorts)  [h][key][d] bf16 hi
//   Klo_g @ 4522496  (262144)                          [h][key][d] bf16 lo
//   Vt_g  @ 4784640  (262144)                          [h*32+d][key] bf16 (pre-transposed)
// total ~20 MB

#define KSPLIT 4

typedef __attribute__((ext_vector_type(8))) short short8;   // 8 bf16
typedef __attribute__((ext_vector_type(4))) short short4v;  // 4 bf16 (8B)
typedef __attribute__((ext_vector_type(4))) float f32x4;

__device__ inline unsigned short f2bf(float x) {            // RNE f32->bf16 bits
    unsigned u = __float_as_uint(x);
    return (unsigned short)((u + 0x7FFFu + ((u >> 16) & 1u)) >> 16);
}
__device__ inline float bf2f(unsigned short h) { return __uint_as_float(((unsigned)h) << 16); }

// ---------------- K1: sine encoding + eig = eeig @ W + b ----------------
__global__ __launch_bounds__(256) void k_eig(const float* __restrict__ eve,
    const float* __restrict__ W, const float* __restrict__ bias,
    float* __restrict__ eig)
{
    __shared__ __align__(16) float se[8][132];    // [0..63]=sin, [64..127]=cos, [128]=e
    const int t = threadIdx.x;
    const int r0 = blockIdx.x * 8;
    {
        const int r = t >> 5, l = t & 31;
        const float e = eve[r0 + r];
        if (l == 0) se[r][128] = e;
        const float e100 = e * 100.0f;
        #pragma unroll
        for (int jj = 0; jj < 2; ++jj) {
            const int j = l * 2 + jj;             // 0..63
            const float div = expf(-0.07195578415606394f * (float)(2 * j));
            const float pe = e100 * div;
            se[r][j]      = sinf(pe);
            se[r][64 + j] = cosf(pe);
        }
    }
    __syncthreads();
    const int c = t & 127;
    const int rg = t >> 7;                        // 0..1; rows rg+2i, i<4
    float acc[4];
    {
        const float w0 = W[c];                    // W row 0 pairs with raw e
        #pragma unroll
        for (int i = 0; i < 4; ++i) acc[i] = se[rg + 2 * i][128] * w0;
    }
    #pragma unroll 4                              // 16 loads in flight, no full-unroll spill
    for (int k = 0; k < 128; k += 4) {            // se[.][k] pairs W[k+1]
        const float w0 = W[(k + 1) * 128 + c];
        const float w1 = W[(k + 2) * 128 + c];
        const float w2 = W[(k + 3) * 128 + c];
        const float w3 = W[(k + 4) * 128 + c];
        #pragma unroll
        for (int i = 0; i < 4; ++i) {
            const float4 x = *(const float4*)&se[rg + 2 * i][k];
            float a = acc[i];
            a = fmaf(x.x, w0, a);
            a = fmaf(x.y, w1, a);
            a = fmaf(x.z, w2, a);
            a = fmaf(x.w, w3, a);
            acc[i] = a;
        }
    }
    const float bb = bias[c];
    #pragma unroll
    for (int i = 0; i < 4; ++i) eig[(r0 + rg + 2 * i) * 128 + c] = acc[i] + bb;
}

// ---------------- K2: LN1 + qkv; Q->f32, K->bf16 hi/lo global, V->bf16 transposed global ----------------
__global__ __launch_bounds__(256) void k_qkv(const float* __restrict__ eig,
    const float* __restrict__ g, const float* __restrict__ b,
    const float* __restrict__ inW, const float* __restrict__ inb,
    float* __restrict__ qkv, unsigned short* __restrict__ Khi_g,
    unsigned short* __restrict__ Klo_g, unsigned short* __restrict__ Vt_g)
{
    __shared__ __align__(16) float xn[8][128];
    __shared__ float red1[8][32];
    __shared__ float red2[8][32];
    __shared__ __align__(16) unsigned short vsh[128][8];   // V bf16, [col][row]
    const int t = threadIdx.x;
    const int r0 = blockIdx.x * 8;
    const int r = t >> 5, l = t & 31;
    float v[4];
    {
        float s = 0.f, ss = 0.f;
        #pragma unroll
        for (int m = 0; m < 4; ++m) {
            const float x = eig[(r0 + r) * 128 + l + 32 * m];
            v[m] = x; s += x; ss += x * x;
        }
        red1[r][l] = s; red2[r][l] = ss;
    }
    __syncthreads();
    for (int o = 16; o > 0; o >>= 1) {
        if (l < o) { red1[r][l] += red1[r][l + o]; red2[r][l] += red2[r][l + o]; }
        __syncthreads();
    }
    {
        const float mean = red1[r][0] * (1.f / 128.f);
        const float var  = red2[r][0] * (1.f / 128.f) - mean * mean;
        const float inv  = 1.f / sqrtf(var + 1e-5f);
        #pragma unroll
        for (int m = 0; m < 4; ++m) {
            const int col = l + 32 * m;
            xn[r][col] = (v[m] - mean) * inv * g[col] + b[col];
        }
    }
    __syncthreads();
    const int cbase = t & 127;
    const int rg = t >> 7;
    float acc[3][4];
    #pragma unroll
    for (int p = 0; p < 3; ++p) {
        const float bb = inb[p * 128 + cbase];
        #pragma unroll
        for (int i = 0; i < 4; ++i) acc[p][i] = bb;
    }
    #pragma unroll 2
    for (int k = 0; k < 128; k += 4) {
        float4 xv[4];
        #pragma unroll
        for (int i = 0; i < 4; ++i) xv[i] = *(const float4*)&xn[rg + 2 * i][k];
        #pragma unroll
        for (int p = 0; p < 3; ++p) {
            const int c = p * 128 + cbase;
            const float w0 = inW[(k + 0) * 384 + c];
            const float w1 = inW[(k + 1) * 384 + c];
            const float w2 = inW[(k + 2) * 384 + c];
            const float w3 = inW[(k + 3) * 384 + c];
            #pragma unroll
            for (int i = 0; i < 4; ++i) {
                float a = acc[p][i];
                a = fmaf(xv[i].x, w0, a);
                a = fmaf(xv[i].y, w1, a);
                a = fmaf(xv[i].z, w2, a);
                a = fmaf(xv[i].w, w3, a);
                acc[p][i] = a;
            }
        }
    }
    // Q: f32 to qkv
    #pragma unroll
    for (int i = 0; i < 4; ++i)
        qkv[(r0 + rg + 2 * i) * 384 + cbase] = acc[0][i];
    // K: bf16 hi/lo, [h][key][d]
    {
        const int h = cbase >> 5, d = cbase & 31;
        #pragma unroll
        for (int i = 0; i < 4; ++i) {
            const int row = r0 + rg + 2 * i;
            const float kv = acc[1][i];
            const unsigned short hb = f2bf(kv);
            Khi_g[((size_t)h * 4096 + row) * 32 + d] = hb;
            Klo_g[((size_t)h * 4096 + row) * 32 + d] = f2bf(kv - bf2f(hb));
        }
    }
    // V: bf16 via LDS transpose -> Vt_g[h*32+d][key]
    #pragma unroll
    for (int i = 0; i < 4; ++i)
        vsh[cbase][rg + 2 * i] = f2bf(acc[2][i]);
    __syncthreads();
    if (t < 128) {
        const uint4 vv = *(const uint4*)&vsh[t][0];   // 8 keys of column t
        *(uint4*)&Vt_g[(size_t)t * 4096 + r0] = vv;
    }
}

// ---------------- K3: MFMA flash attention (no-max linear partials) ----------------
// Pre-converted bf16 K/V from global; staging = 16B load + ds_write_b128 (bank-floor).
// QK^T computed TRANSPOSED (A=K-frag, B=Q-frag -> D[key][query]): lane holds 4 consecutive
// keys for one query -> P store is one aligned b64; E-reduce = 2 shuffles.
// PV: A=P[query][key] rows, B=Vt[d][key] rows (both contiguous short8).
#define KSTR 40
#define VSTR 72
#define PSTR 72

__global__ __launch_bounds__(256) void k_attn(const float* __restrict__ qkv,
    const unsigned short* __restrict__ Khi_g, const unsigned short* __restrict__ Klo_g,
    const unsigned short* __restrict__ Vt_g,
    const int* __restrict__ sele, float* __restrict__ Oe, float* __restrict__ E)
{
    __shared__ __align__(16) unsigned short Khi[64 * KSTR];
    __shared__ __align__(16) unsigned short Klo[64 * KSTR];
    __shared__ __align__(16) unsigned short Vt[32 * VSTR];
    __shared__ __align__(16) unsigned short Pb[4][16 * PSTR];

    const int t = threadIdx.x;
    const int lane = t & 63;
    const int l = lane & 15;
    const int quad = lane >> 4;
    const int wv = __builtin_amdgcn_readfirstlane(t >> 6);
    const int qb = blockIdx.x;   // 64 q-blocks of 64
    const int h  = blockIdx.y;   // 4 heads
    const int ks = blockIdx.z;   // 4 key slots of 1024
    const int nk = sele[0];

    // Q B-fragment: query = qb*64 + wv*16 + l; k-dim d = quad*8 + j. Scale, split hi/lo.
    short8 qhi, qlo;
    {
        const float* __restrict__ qr = qkv + (size_t)(qb * 64 + wv * 16 + l) * 384 + h * 32 + quad * 8;
        const float4 a = *(const float4*)qr;
        const float4 b = *(const float4*)(qr + 4);
        const float sc = 0.17677669529663687f;   // 1/sqrt(32)
        float v[8] = {a.x * sc, a.y * sc, a.z * sc, a.w * sc, b.x * sc, b.y * sc, b.z * sc, b.w * sc};
        #pragma unroll
        for (int j = 0; j < 8; ++j) {
            const unsigned short hb = f2bf(v[j]);
            qhi[j] = (short)hb;
            qlo[j] = (short)f2bf(v[j] - bf2f(hb));
        }
    }
    f32x4 accO0 = {0.f, 0.f, 0.f, 0.f};
    f32x4 accO1 = {0.f, 0.f, 0.f, 0.f};
    float elane = 0.f;                     // exp-sum for query l (this wave's subtile)

    // staging thread maps (block-wide)
    const int kk = t >> 2;                 // 0..63 key for K staging
    const int d0 = (t & 3) * 8;            // d-octet for K staging
    const int vd = t >> 3;                 // 0..31 d for V staging
    const int ko = (t & 7) * 8;            // key-octet for V staging

    for (int ch = 0; ch < 16; ++ch) {
        const int keybase = ks * 1024 + ch * 64;
        __syncthreads();                   // previous chunk fully consumed
        {   // stage K hi/lo [key][d] and V [d][key] — pure 16B copies
            const uint4 kh16 = *(const uint4*)&Khi_g[((size_t)h * 4096 + keybase + kk) * 32 + d0];
            const uint4 kl16 = *(const uint4*)&Klo_g[((size_t)h * 4096 + keybase + kk) * 32 + d0];
            const uint4 vv16 = *(const uint4*)&Vt_g[((size_t)h * 32 + vd) * 4096 + keybase + ko];
            *(uint4*)&Khi[kk * KSTR + d0] = kh16;
            *(uint4*)&Klo[kk * KSTR + d0] = kl16;
            *(uint4*)&Vt[vd * VSTR + ko]  = vv16;
        }
        __syncthreads();
        unsigned short* __restrict__ Pw = Pb[wv];
        // QK^T transposed: D[key-in-tile][query]
        #pragma unroll
        for (int tile = 0; tile < 4; ++tile) {
            const int kl = tile * 16 + l;
            const short8 kh = *(const short8*)&Khi[kl * KSTR + quad * 8];
            const short8 kw = *(const short8*)&Klo[kl * KSTR + quad * 8];
            f32x4 S = {0.f, 0.f, 0.f, 0.f};
            S = __builtin_amdgcn_mfma_f32_16x16x32_bf16(kh, qhi, S, 0, 0, 0);
            S = __builtin_amdgcn_mfma_f32_16x16x32_bf16(kw, qhi, S, 0, 0, 0);
            S = __builtin_amdgcn_mfma_f32_16x16x32_bf16(kh, qlo, S, 0, 0, 0);
            const int kg0 = keybase + tile * 16 + quad * 4;   // lane's 4 consecutive keys
            short4v pw;
            #pragma unroll
            for (int r = 0; r < 4; ++r) {
                const float p = (kg0 + r < nk) ? __expf(S[r]) : 0.f;
                elane += p;
                pw[r] = (short)f2bf(p);
            }
            *(short4v*)&Pw[l * PSTR + tile * 16 + quad * 4] = pw;   // aligned 8B, bank-floor
        }
        // PV: 2 k-steps of 32 keys x 2 d-tiles of 16
        #pragma unroll
        for (int step = 0; step < 2; ++step) {
            const short8 pa  = *(const short8*)&Pw[l * PSTR + step * 32 + quad * 8];
            const short8 vb0 = *(const short8*)&Vt[l * VSTR + step * 32 + quad * 8];
            const short8 vb1 = *(const short8*)&Vt[(16 + l) * VSTR + step * 32 + quad * 8];
            accO0 = __builtin_amdgcn_mfma_f32_16x16x32_bf16(pa, vb0, accO0, 0, 0, 0);
            accO1 = __builtin_amdgcn_mfma_f32_16x16x32_bf16(pa, vb1, accO1, 0, 0, 0);
        }
    }
    // E: lane's partial covers its quad's keys; sum across quads (same query l)
    elane += __shfl_xor(elane, 16, 64);
    elane += __shfl_xor(elane, 32, 64);
    const int qrow0 = qb * 64 + wv * 16;
    if (lane < 16)
        E[((size_t)ks * 4 + h) * 4096 + qrow0 + l] = elane;
    #pragma unroll
    for (int r = 0; r < 4; ++r) {
        const size_t row = qrow0 + quad * 4 + r;
        Oe[((size_t)ks * 4096 + row) * 128 + h * 32 + l]      = accO0[r];
        Oe[((size_t)ks * 4096 + row) * 128 + h * 32 + 16 + l] = accO1[r];
    }
}

// ---------------- K4: fold Oe/E + out-proj + residual + LN2 + FFN + residual + column-sum ----------------
__global__ __launch_bounds__(256) void k_ffn(const float* __restrict__ eig,
    const float* __restrict__ Oe, const float* __restrict__ E,
    const float* __restrict__ outW, const float* __restrict__ outb,
    const float* __restrict__ lg, const float* __restrict__ lb,
    const float* __restrict__ W1, const float* __restrict__ b1,
    const float* __restrict__ W2, const float* __restrict__ b2,
    const int* __restrict__ sele, float* __restrict__ xsum)
{
    __shared__ __align__(16) float sA[8][128];    // attention O rows, later gelu(h)
    __shared__ __align__(16) float x2[8][128];    // residual stream
    __shared__ __align__(16) float xn[8][128];    // LN2 output
    __shared__ float red1[8][32];
    __shared__ float red2[8][32];
    __shared__ float sEr[8][4];
    __shared__ float colsum[2][128];
    const int t = threadIdx.x;
    const int r0 = blockIdx.x * 8;
    const int r = t >> 5, l = t & 31;
    if (l < 4) {                                   // per-(row,head) reciprocal exp-sum
        float es = 0.f;
        #pragma unroll
        for (int ks = 0; ks < KSPLIT; ++ks)
            es += E[((size_t)ks * 4 + l) * 4096 + r0 + r];
        sEr[r][l] = 1.f / es;
    }
    __syncthreads();
    #pragma unroll
    for (int m = 0; m < 4; ++m) {                  // fold 4 slots -> O row
        const int col = l + 32 * m;
        float v = 0.f;
        #pragma unroll
        for (int ks = 0; ks < KSPLIT; ++ks)
            v += Oe[((size_t)ks * 4096 + r0 + r) * 128 + col];
        sA[r][col] = v * sEr[r][col >> 5];
    }
    __syncthreads();
    const int c = t & 127;
    const int rg = t >> 7;
    {   // out projection + residual
        float acc[4];
        const float bb = outb[c];
        #pragma unroll
        for (int i = 0; i < 4; ++i) acc[i] = bb;
        #pragma unroll 4
        for (int k = 0; k < 128; k += 4) {
            const float w0 = outW[(k + 0) * 128 + c];
            const float w1 = outW[(k + 1) * 128 + c];
            const float w2 = outW[(k + 2) * 128 + c];
            const float w3 = outW[(k + 3) * 128 + c];
            #pragma unroll
            for (int i = 0; i < 4; ++i) {
                const float4 x = *(const float4*)&sA[rg + 2 * i][k];
                float a = acc[i];
                a = fmaf(x.x, w0, a);
                a = fmaf(x.y, w1, a);
                a = fmaf(x.z, w2, a);
                a = fmaf(x.w, w3, a);
                acc[i] = a;
            }
        }
        #pragma unroll
        for (int i = 0; i < 4; ++i)
            x2[rg + 2 * i][c] = eig[(r0 + rg + 2 * i) * 128 + c] + acc[i];
    }
    __syncthreads();
    {   // LN2
        float s = 0.f, ss = 0.f;
        float v[4];
        #pragma unroll
        for (int m = 0; m < 4; ++m) {
            const float x = x2[r][l + 32 * m];
            v[m] = x; s += x; ss += x * x;
        }
        red1[r][l] = s; red2[r][l] = ss;
        __syncthreads();
        for (int o = 16; o > 0; o >>= 1) {
            if (l < o) { red1[r][l] += red1[r][l + o]; red2[r][l] += red2[r][l + o]; }
            __syncthreads();
        }
        const float mean = red1[r][0] * (1.f / 128.f);
        const float var  = red2[r][0] * (1.f / 128.f) - mean * mean;
        const float inv  = 1.f / sqrtf(var + 1e-5f);
        #pragma unroll
        for (int m = 0; m < 4; ++m) {
            const int col = l + 32 * m;
            xn[r][col] = (v[m] - mean) * inv * lg[col] + lb[col];
        }
    }
    __syncthreads();
    {   // FFN1 + exact gelu -> sA
        float acc[4];
        const float bb = b1[c];
        #pragma unroll
        for (int i = 0; i < 4; ++i) acc[i] = bb;
        #pragma unroll 4
        for (int k = 0; k < 128; k += 4) {
            const float w0 = W1[(k + 0) * 128 + c];
            const float w1 = W1[(k + 1) * 128 + c];
            const float w2 = W1[(k + 2) * 128 + c];
            const float w3 = W1[(k + 3) * 128 + c];
            #pragma unroll
            for (int i = 0; i < 4; ++i) {
                const float4 x = *(const float4*)&xn[rg + 2 * i][k];
                float a = acc[i];
                a = fmaf(x.x, w0, a);
                a = fmaf(x.y, w1, a);
                a = fmaf(x.z, w2, a);
                a = fmaf(x.w, w3, a);
                acc[i] = a;
            }
        }
        __syncthreads();
        #pragma unroll
        for (int i = 0; i < 4; ++i) {
            const float x = acc[i];
            sA[rg + 2 * i][c] = 0.5f * x * (1.f + erff(x * 0.70710678118654752f));
        }
    }
    __syncthreads();
    {   // FFN2 + residual + masked column sum
        float acc[4];
        const float bb = b2[c];
        #pragma unroll
        for (int i = 0; i < 4; ++i) acc[i] = bb;
        #pragma unroll 4
        for (int k = 0; k < 128; k += 4) {
            const float w0 = W2[(k + 0) * 128 + c];
            const float w1 = W2[(k + 1) * 128 + c];
            const float w2 = W2[(k + 2) * 128 + c];
            const float w3 = W2[(k + 3) * 128 + c];
            #pragma unroll
            for (int i = 0; i < 4; ++i) {
                const float4 x = *(const float4*)&sA[rg + 2 * i][k];
                float a = acc[i];
                a = fmaf(x.x, w0, a);
                a = fmaf(x.y, w1, a);
                a = fmaf(x.z, w2, a);
                a = fmaf(x.w, w3, a);
                acc[i] = a;
            }
        }
        const int nsel = sele[0];
        float local = 0.f;
        #pragma unroll
        for (int i = 0; i < 4; ++i) {
            const float ef = x2[rg + 2 * i][c] + acc[i];
            if (r0 + rg + 2 * i < nsel) local += ef;
        }
        colsum[rg][c] = local;
    }
    __syncthreads();
    if (rg == 0) atomicAdd(&xsum[c], colsum[0][c] + colsum[1][c]);
}

// ---------------- K5: pooled coefficients ----------------
__global__ __launch_bounds__(128) void k_coef(const float* __restrict__ xsum,
    const float* __restrict__ dscW, const float* __restrict__ dscb,
    const float* __restrict__ dwvW, const float* __restrict__ dwvb,
    const float* __restrict__ dssW, const float* __restrict__ dssb,
    const int* __restrict__ len, const int* __restrict__ sele,
    float* __restrict__ coef)
{
    __shared__ float xs[128];
    __shared__ float csc[50], cwv[50];
    __shared__ float s2[2];
    const int t = threadIdx.x;
    xs[t] = xsum[t];
    __syncthreads();
    const float invl = 1.f / ((float)len[0] + 1e-8f);
    const float ns = (float)sele[0];
    if (t < 50) {
        float a = ns * dscb[t];
        for (int k = 0; k < 128; ++k) a = fmaf(xs[k], dscW[k * 50 + t], a);
        a *= invl;
        csc[t] = 1.f / (1.f + expf(-a));
    } else if (t >= 64 && t < 114) {
        const int j = t - 64;
        float a = ns * dwvb[j];
        for (int k = 0; k < 128; ++k) a = fmaf(xs[k], dwvW[k * 50 + j], a);
        a *= invl;
        cwv[j] = 1.f / (1.f + expf(-a));
    } else if (t >= 114 && t < 118) {
        const int j = t - 114;
        float a = ns * dssb[j];
        for (int k = 0; k < 128; ++k) a = fmaf(xs[k], dssW[k * 4 + j], a);
        a *= invl;
        coef[100 + j] = (1.f / (1.f + expf(-a))) * 5.0f;  // THRE
    }
    __syncthreads();
    if (t == 0) { float s = 0.f; for (int i2 = 0; i2 < 50; ++i2) s += csc[i2]; s2[0] = s; }
    if (t == 1) { float s = 0.f; for (int i2 = 0; i2 < 50; ++i2) s += cwv[i2]; s2[1] = s; }
    __syncthreads();
    if (t < 50) {
        coef[t]      = csc[t] / (s2[0] + 1e-8f);
        coef[50 + t] = cwv[t] / (s2[1] + 1e-8f);
    }
}

// ---------------- K6: Chebyshev bases + combine + normalize ----------------
__global__ __launch_bounds__(256) void k_out(const float* __restrict__ eve,
    const float* __restrict__ coef, float* __restrict__ out)
{
    __shared__ float csc[50], cwv[50], cs[4];
    const int t = threadIdx.x;
    if (t < 50) csc[t] = coef[t];
    else if (t < 100) cwv[t - 50] = coef[t];
    else if (t < 104) cs[t - 100] = coef[t];
    __syncthreads();
    const int s = blockIdx.x * 256 + t;
    const float e = eve[s];
    float vals[5];
    {   // scaling: [T1, T3, ..., T99](e-1); 0.5*(1-T)
        const float y = e - 1.f;
        float te = 1.f, to = y;
        float a = csc[0] * (0.5f * (1.f - to));
        const float y2 = 2.f * y;
        for (int i = 1; i < 50; ++i) {
            te = fmaf(y2, to, -te);
            to = fmaf(y2, te, -to);
            a = fmaf(csc[i], 0.5f * (1.f - to), a);
        }
        vals[0] = a;
    }
    #pragma unroll
    for (int j = 0; j < 4; ++j) {  // wavelet: [T0, T2, ..., T98](fsw-1)
        float f = e * cs[j];
        if (f > 2.f) f = 0.f;
        const float y = f - 1.f;
        float te = 1.f, to = y;
        float a = cwv[0] * (0.5f * (1.f - te));
        const float y2 = 2.f * y;
        for (int i = 1; i < 50; ++i) {
            te = fmaf(y2, to, -te);
            to = fmaf(y2, te, -to);
            a = fmaf(cwv[i], 0.5f * (1.f - te), a);
        }
        vals[1 + j] = a;
    }
    float n2 = 0.f;
    #pragma unroll
    for (int k = 0; k < 5; ++k) n2 += vals[k] * vals[k];
    const float invn = 1.f / (sqrtf(n2) + 1e-8f);
    #pragma unroll
    for (int k = 0; k < 5; ++k) out[s * 5 + k] = vals[k] * invn;
}

extern "C" void kernel_launch(void* const* d_in, const int* in_sizes, int n_in,
                              void* d_out, int out_size, void* d_ws, size_t ws_size,
                              hipStream_t stream) {
    const float* eve  = (const float*)d_in[0];
    const int*   len  = (const int*)d_in[1];
    const int*   sele = (const int*)d_in[2];
    const float* eigW = (const float*)d_in[3];
    const float* eigB = (const float*)d_in[4];
    const float* mlg  = (const float*)d_in[5];
    const float* mlb  = (const float*)d_in[6];
    const float* inW  = (const float*)d_in[7];
    const float* inb  = (const float*)d_in[8];
    const float* outW = (const float*)d_in[9];
    const float* outb = (const float*)d_in[10];
    const float* flg  = (const float*)d_in[11];
    const float* flb  = (const float*)d_in[12];
    const float* W1   = (const float*)d_in[13];
    const float* b1   = (const float*)d_in[14];
    const float* W2   = (const float*)d_in[15];
    const float* b2   = (const float*)d_in[16];
    const float* dscW = (const float*)d_in[17];
    const float* dscb = (const float*)d_in[18];
    const float* dwvW = (const float*)d_in[19];
    const float* dwvb = (const float*)d_in[20];
    const float* dssW = (const float*)d_in[21];
    const float* dssb = (const float*)d_in[22];

    float* ws   = (float*)d_ws;
    float* eig  = ws;
    float* qkv  = ws + 524288;
    float* Oe   = ws + 2097152;
    float* E    = ws + 4194304;
    float* xsum = ws + 4259840;
    float* coef = ws + 4259968;
    unsigned short* Khi_g = (unsigned short*)(ws + 4260352);
    unsigned short* Klo_g = (unsigned short*)(ws + 4522496);
    unsigned short* Vt_g  = (unsigned short*)(ws + 4784640);
    float* out  = (float*)d_out;

    hipMemsetAsync(xsum, 0, 128 * sizeof(float), stream);
    k_eig <<<512, 256, 0, stream>>>(eve, eigW, eigB, eig);
    k_qkv <<<512, 256, 0, stream>>>(eig, mlg, mlb, inW, inb, qkv, Khi_g, Klo_g, Vt_g);
    k_attn<<<dim3(64, 4, KSPLIT), 256, 0, stream>>>(qkv, Khi_g, Klo_g, Vt_g, sele, Oe, E);
    k_ffn <<<512, 256, 0, stream>>>(eig, Oe, E, outW, outb, flg, flb, W1, b1, W2, b2, sele, xsum);
    k_coef<<<1, 128, 0, stream>>>(xsum, dscW, dscb, dwvW, dwvb, dssW, dssb, len, sele, coef);
    k_out <<<16, 256, 0, stream>>>(eve, coef, out);
}

// Round 9
// 207.617 us; speedup vs baseline: 2.0971x; 1.0263x over previous
//
#include <hip/hip_runtime.h>
#include <math.h>

// Problem constants (B=1): S=4096, D=128, NHEADS=4, hd=32, N_COE=50, N_SCALES=4, THRE=5
//
// ws layout (floats):
//   eig   @ 0        (524288)
//   qkv   @ 524288   (1572864; only Q panel [.,0..127] written/used in f32)
//   Oe    @ 2097152  (4*4096*128 = 2097152)
//   E     @ 4194304  (4*4*4096 = 65536)
//   xsum  @ 4259840  (128)
//   coef  @ 4259968  (104; pad to 384)
//   Khi_g @ 4260352  (262144 floats = 524288 ushorts)  [h][key][d] bf16 hi
//   Klo_g @ 4522496  (262144)                          [h][key][d] bf16 lo
//   Vt_g  @ 4784640  (262144)                          [h*32+d][key] bf16 (pre-transposed)
// total ~20 MB

#define KSPLIT 4

typedef __attribute__((ext_vector_type(8))) short short8;   // 8 bf16
typedef __attribute__((ext_vector_type(4))) short short4v;  // 4 bf16 (8B)
typedef __attribute__((ext_vector_type(4))) float f32x4;

__device__ inline unsigned short f2bf(float x) {            // RNE f32->bf16 bits
    unsigned u = __float_as_uint(x);
    return (unsigned short)((u + 0x7FFFu + ((u >> 16) & 1u)) >> 16);
}
__device__ inline float bf2f(unsigned short h) { return __uint_as_float(((unsigned)h) << 16); }

// ---------------- K1: sine encoding + eig = eeig @ W + b ----------------
__global__ __launch_bounds__(256) void k_eig(const float* __restrict__ eve,
    const float* __restrict__ W, const float* __restrict__ bias,
    float* __restrict__ eig)
{
    __shared__ __align__(16) float se[8][132];    // [0..63]=sin, [64..127]=cos, [128]=e
    const int t = threadIdx.x;
    const int r0 = blockIdx.x * 8;
    {
        const int r = t >> 5, l = t & 31;
        const float e = eve[r0 + r];
        if (l == 0) se[r][128] = e;
        const float e100 = e * 100.0f;
        #pragma unroll
        for (int jj = 0; jj < 2; ++jj) {
            const int j = l * 2 + jj;             // 0..63
            const float div = __expf(-0.07195578415606394f * (float)(2 * j));
            const float pe = e100 * div;          // |pe| <= 200 rad: __sinf err ~1e-5 (ok)
            se[r][j]      = __sinf(pe);
            se[r][64 + j] = __cosf(pe);
        }
    }
    __syncthreads();
    const int c = t & 127;
    const int rg = t >> 7;                        // 0..1; rows rg+2i, i<4
    float acc[4];
    {
        const float w0 = W[c];                    // W row 0 pairs with raw e
        #pragma unroll
        for (int i = 0; i < 4; ++i) acc[i] = se[rg + 2 * i][128] * w0;
    }
    #pragma unroll 8                              // 32 loads in flight (grid-limited occupancy -> ILP)
    for (int k = 0; k < 128; k += 4) {            // se[.][k] pairs W[k+1]
        const float w0 = W[(k + 1) * 128 + c];
        const float w1 = W[(k + 2) * 128 + c];
        const float w2 = W[(k + 3) * 128 + c];
        const float w3 = W[(k + 4) * 128 + c];
        #pragma unroll
        for (int i = 0; i < 4; ++i) {
            const float4 x = *(const float4*)&se[rg + 2 * i][k];
            float a = acc[i];
            a = fmaf(x.x, w0, a);
            a = fmaf(x.y, w1, a);
            a = fmaf(x.z, w2, a);
            a = fmaf(x.w, w3, a);
            acc[i] = a;
        }
    }
    const float bb = bias[c];
    #pragma unroll
    for (int i = 0; i < 4; ++i) eig[(r0 + rg + 2 * i) * 128 + c] = acc[i] + bb;
}

// ---------------- K2: LN1 + qkv; Q->f32, K->bf16 hi/lo global, V->bf16 transposed global ----------------
__global__ __launch_bounds__(256) void k_qkv(const float* __restrict__ eig,
    const float* __restrict__ g, const float* __restrict__ b,
    const float* __restrict__ inW, const float* __restrict__ inb,
    float* __restrict__ qkv, unsigned short* __restrict__ Khi_g,
    unsigned short* __restrict__ Klo_g, unsigned short* __restrict__ Vt_g)
{
    __shared__ __align__(16) float xn[8][128];
    __shared__ float red1[8][32];
    __shared__ float red2[8][32];
    __shared__ __align__(16) unsigned short vsh[128][8];   // V bf16, [col][row]
    const int t = threadIdx.x;
    const int r0 = blockIdx.x * 8;
    const int r = t >> 5, l = t & 31;
    float v[4];
    {
        float s = 0.f, ss = 0.f;
        #pragma unroll
        for (int m = 0; m < 4; ++m) {
            const float x = eig[(r0 + r) * 128 + l + 32 * m];
            v[m] = x; s += x; ss += x * x;
        }
        red1[r][l] = s; red2[r][l] = ss;
    }
    __syncthreads();
    for (int o = 16; o > 0; o >>= 1) {
        if (l < o) { red1[r][l] += red1[r][l + o]; red2[r][l] += red2[r][l + o]; }
        __syncthreads();
    }
    {
        const float mean = red1[r][0] * (1.f / 128.f);
        const float var  = red2[r][0] * (1.f / 128.f) - mean * mean;
        const float inv  = 1.f / sqrtf(var + 1e-5f);
        #pragma unroll
        for (int m = 0; m < 4; ++m) {
            const int col = l + 32 * m;
            xn[r][col] = (v[m] - mean) * inv * g[col] + b[col];
        }
    }
    __syncthreads();
    const int cbase = t & 127;
    const int rg = t >> 7;
    float acc[3][4];
    #pragma unroll
    for (int p = 0; p < 3; ++p) {
        const float bb = inb[p * 128 + cbase];
        #pragma unroll
        for (int i = 0; i < 4; ++i) acc[p][i] = bb;
    }
    #pragma unroll 4                              // 48 loads in flight
    for (int k = 0; k < 128; k += 4) {
        float4 xv[4];
        #pragma unroll
        for (int i = 0; i < 4; ++i) xv[i] = *(const float4*)&xn[rg + 2 * i][k];
        #pragma unroll
        for (int p = 0; p < 3; ++p) {
            const int c = p * 128 + cbase;
            const float w0 = inW[(k + 0) * 384 + c];
            const float w1 = inW[(k + 1) * 384 + c];
            const float w2 = inW[(k + 2) * 384 + c];
            const float w3 = inW[(k + 3) * 384 + c];
            #pragma unroll
            for (int i = 0; i < 4; ++i) {
                float a = acc[p][i];
                a = fmaf(xv[i].x, w0, a);
                a = fmaf(xv[i].y, w1, a);
                a = fmaf(xv[i].z, w2, a);
                a = fmaf(xv[i].w, w3, a);
                acc[p][i] = a;
            }
        }
    }
    // Q: f32 to qkv
    #pragma unroll
    for (int i = 0; i < 4; ++i)
        qkv[(r0 + rg + 2 * i) * 384 + cbase] = acc[0][i];
    // K: bf16 hi/lo, [h][key][d]
    {
        const int h = cbase >> 5, d = cbase & 31;
        #pragma unroll
        for (int i = 0; i < 4; ++i) {
            const int row = r0 + rg + 2 * i;
            const float kv = acc[1][i];
            const unsigned short hb = f2bf(kv);
            Khi_g[((size_t)h * 4096 + row) * 32 + d] = hb;
            Klo_g[((size_t)h * 4096 + row) * 32 + d] = f2bf(kv - bf2f(hb));
        }
    }
    // V: bf16 via LDS transpose -> Vt_g[h*32+d][key]
    #pragma unroll
    for (int i = 0; i < 4; ++i)
        vsh[cbase][rg + 2 * i] = f2bf(acc[2][i]);
    __syncthreads();
    if (t < 128) {
        const uint4 vv = *(const uint4*)&vsh[t][0];   // 8 keys of column t
        *(uint4*)&Vt_g[(size_t)t * 4096 + r0] = vv;
    }
}

// ---------------- K3: MFMA flash attention (no-max linear partials) ----------------
#define KSTR 40
#define VSTR 72
#define PSTR 72

__global__ __launch_bounds__(256) void k_attn(const float* __restrict__ qkv,
    const unsigned short* __restrict__ Khi_g, const unsigned short* __restrict__ Klo_g,
    const unsigned short* __restrict__ Vt_g,
    const int* __restrict__ sele, float* __restrict__ Oe, float* __restrict__ E)
{
    __shared__ __align__(16) unsigned short Khi[64 * KSTR];
    __shared__ __align__(16) unsigned short Klo[64 * KSTR];
    __shared__ __align__(16) unsigned short Vt[32 * VSTR];
    __shared__ __align__(16) unsigned short Pb[4][16 * PSTR];

    const int t = threadIdx.x;
    const int lane = t & 63;
    const int l = lane & 15;
    const int quad = lane >> 4;
    const int wv = __builtin_amdgcn_readfirstlane(t >> 6);
    const int qb = blockIdx.x;   // 64 q-blocks of 64
    const int h  = blockIdx.y;   // 4 heads
    const int ks = blockIdx.z;   // 4 key slots of 1024
    const int nk = sele[0];

    // Q B-fragment: query = qb*64 + wv*16 + l; k-dim d = quad*8 + j. Scale, split hi/lo.
    short8 qhi, qlo;
    {
        const float* __restrict__ qr = qkv + (size_t)(qb * 64 + wv * 16 + l) * 384 + h * 32 + quad * 8;
        const float4 a = *(const float4*)qr;
        const float4 b = *(const float4*)(qr + 4);
        const float sc = 0.17677669529663687f;   // 1/sqrt(32)
        float v[8] = {a.x * sc, a.y * sc, a.z * sc, a.w * sc, b.x * sc, b.y * sc, b.z * sc, b.w * sc};
        #pragma unroll
        for (int j = 0; j < 8; ++j) {
            const unsigned short hb = f2bf(v[j]);
            qhi[j] = (short)hb;
            qlo[j] = (short)f2bf(v[j] - bf2f(hb));
        }
    }
    f32x4 accO0 = {0.f, 0.f, 0.f, 0.f};
    f32x4 accO1 = {0.f, 0.f, 0.f, 0.f};
    float elane = 0.f;

    const int kk = t >> 2;                 // 0..63 key for K staging
    const int d0 = (t & 3) * 8;            // d-octet for K staging
    const int vd = t >> 3;                 // 0..31 d for V staging
    const int ko = (t & 7) * 8;            // key-octet for V staging

    for (int ch = 0; ch < 16; ++ch) {
        const int keybase = ks * 1024 + ch * 64;
        __syncthreads();
        {   // stage K hi/lo [key][d] and V [d][key] — pure 16B copies
            const uint4 kh16 = *(const uint4*)&Khi_g[((size_t)h * 4096 + keybase + kk) * 32 + d0];
            const uint4 kl16 = *(const uint4*)&Klo_g[((size_t)h * 4096 + keybase + kk) * 32 + d0];
            const uint4 vv16 = *(const uint4*)&Vt_g[((size_t)h * 32 + vd) * 4096 + keybase + ko];
            *(uint4*)&Khi[kk * KSTR + d0] = kh16;
            *(uint4*)&Klo[kk * KSTR + d0] = kl16;
            *(uint4*)&Vt[vd * VSTR + ko]  = vv16;
        }
        __syncthreads();
        unsigned short* __restrict__ Pw = Pb[wv];
        // QK^T transposed: D[key-in-tile][query]
        #pragma unroll
        for (int tile = 0; tile < 4; ++tile) {
            const int kl = tile * 16 + l;
            const short8 kh = *(const short8*)&Khi[kl * KSTR + quad * 8];
            const short8 kw = *(const short8*)&Klo[kl * KSTR + quad * 8];
            f32x4 S = {0.f, 0.f, 0.f, 0.f};
            S = __builtin_amdgcn_mfma_f32_16x16x32_bf16(kh, qhi, S, 0, 0, 0);
            S = __builtin_amdgcn_mfma_f32_16x16x32_bf16(kw, qhi, S, 0, 0, 0);
            S = __builtin_amdgcn_mfma_f32_16x16x32_bf16(kh, qlo, S, 0, 0, 0);
            const int kg0 = keybase + tile * 16 + quad * 4;
            short4v pw;
            #pragma unroll
            for (int r = 0; r < 4; ++r) {
                const float p = (kg0 + r < nk) ? __expf(S[r]) : 0.f;
                elane += p;
                pw[r] = (short)f2bf(p);
            }
            *(short4v*)&Pw[l * PSTR + tile * 16 + quad * 4] = pw;
        }
        // PV: 2 k-steps of 32 keys x 2 d-tiles of 16
        #pragma unroll
        for (int step = 0; step < 2; ++step) {
            const short8 pa  = *(const short8*)&Pw[l * PSTR + step * 32 + quad * 8];
            const short8 vb0 = *(const short8*)&Vt[l * VSTR + step * 32 + quad * 8];
            const short8 vb1 = *(const short8*)&Vt[(16 + l) * VSTR + step * 32 + quad * 8];
            accO0 = __builtin_amdgcn_mfma_f32_16x16x32_bf16(pa, vb0, accO0, 0, 0, 0);
            accO1 = __builtin_amdgcn_mfma_f32_16x16x32_bf16(pa, vb1, accO1, 0, 0, 0);
        }
    }
    elane += __shfl_xor(elane, 16, 64);
    elane += __shfl_xor(elane, 32, 64);
    const int qrow0 = qb * 64 + wv * 16;
    if (lane < 16)
        E[((size_t)ks * 4 + h) * 4096 + qrow0 + l] = elane;
    #pragma unroll
    for (int r = 0; r < 4; ++r) {
        const size_t row = qrow0 + quad * 4 + r;
        Oe[((size_t)ks * 4096 + row) * 128 + h * 32 + l]      = accO0[r];
        Oe[((size_t)ks * 4096 + row) * 128 + h * 32 + 16 + l] = accO1[r];
    }
}

// ---------------- K4: fold Oe/E + out-proj + residual + LN2 + FFN + residual + column-sum ----------------
__global__ __launch_bounds__(256) void k_ffn(const float* __restrict__ eig,
    const float* __restrict__ Oe, const float* __restrict__ E,
    const float* __restrict__ outW, const float* __restrict__ outb,
    const float* __restrict__ lg, const float* __restrict__ lb,
    const float* __restrict__ W1, const float* __restrict__ b1,
    const float* __restrict__ W2, const float* __restrict__ b2,
    const int* __restrict__ sele, float* __restrict__ xsum)
{
    __shared__ __align__(16) float sA[8][128];    // attention O rows, later gelu(h)
    __shared__ __align__(16) float x2[8][128];    // residual stream
    __shared__ __align__(16) float xn[8][128];    // LN2 output
    __shared__ float red1[8][32];
    __shared__ float red2[8][32];
    __shared__ float sEr[8][4];
    __shared__ float colsum[2][128];
    const int t = threadIdx.x;
    const int r0 = blockIdx.x * 8;
    const int r = t >> 5, l = t & 31;
    if (l < 4) {
        float es = 0.f;
        #pragma unroll
        for (int ks = 0; ks < KSPLIT; ++ks)
            es += E[((size_t)ks * 4 + l) * 4096 + r0 + r];
        sEr[r][l] = 1.f / es;
    }
    __syncthreads();
    #pragma unroll
    for (int m = 0; m < 4; ++m) {
        const int col = l + 32 * m;
        float v = 0.f;
        #pragma unroll
        for (int ks = 0; ks < KSPLIT; ++ks)
            v += Oe[((size_t)ks * 4096 + r0 + r) * 128 + col];
        sA[r][col] = v * sEr[r][col >> 5];
    }
    __syncthreads();
    const int c = t & 127;
    const int rg = t >> 7;
    {   // out projection + residual
        float acc[4];
        const float bb = outb[c];
        #pragma unroll
        for (int i = 0; i < 4; ++i) acc[i] = bb;
        #pragma unroll 8                           // 32 loads in flight (ILP vs L2 latency)
        for (int k = 0; k < 128; k += 4) {
            const float w0 = outW[(k + 0) * 128 + c];
            const float w1 = outW[(k + 1) * 128 + c];
            const float w2 = outW[(k + 2) * 128 + c];
            const float w3 = outW[(k + 3) * 128 + c];
            #pragma unroll
            for (int i = 0; i < 4; ++i) {
                const float4 x = *(const float4*)&sA[rg + 2 * i][k];
                float a = acc[i];
                a = fmaf(x.x, w0, a);
                a = fmaf(x.y, w1, a);
                a = fmaf(x.z, w2, a);
                a = fmaf(x.w, w3, a);
                acc[i] = a;
            }
        }
        #pragma unroll
        for (int i = 0; i < 4; ++i)
            x2[rg + 2 * i][c] = eig[(r0 + rg + 2 * i) * 128 + c] + acc[i];
    }
    __syncthreads();
    {   // LN2
        float s = 0.f, ss = 0.f;
        float v[4];
        #pragma unroll
        for (int m = 0; m < 4; ++m) {
            const float x = x2[r][l + 32 * m];
            v[m] = x; s += x; ss += x * x;
        }
        red1[r][l] = s; red2[r][l] = ss;
        __syncthreads();
        for (int o = 16; o > 0; o >>= 1) {
            if (l < o) { red1[r][l] += red1[r][l + o]; red2[r][l] += red2[r][l + o]; }
            __syncthreads();
        }
        const float mean = red1[r][0] * (1.f / 128.f);
        const float var  = red2[r][0] * (1.f / 128.f) - mean * mean;
        const float inv  = 1.f / sqrtf(var + 1e-5f);
        #pragma unroll
        for (int m = 0; m < 4; ++m) {
            const int col = l + 32 * m;
            xn[r][col] = (v[m] - mean) * inv * lg[col] + lb[col];
        }
    }
    __syncthreads();
    {   // FFN1 + exact gelu -> sA
        float acc[4];
        const float bb = b1[c];
        #pragma unroll
        for (int i = 0; i < 4; ++i) acc[i] = bb;
        #pragma unroll 8
        for (int k = 0; k < 128; k += 4) {
            const float w0 = W1[(k + 0) * 128 + c];
            const float w1 = W1[(k + 1) * 128 + c];
            const float w2 = W1[(k + 2) * 128 + c];
            const float w3 = W1[(k + 3) * 128 + c];
            #pragma unroll
            for (int i = 0; i < 4; ++i) {
                const float4 x = *(const float4*)&xn[rg + 2 * i][k];
                float a = acc[i];
                a = fmaf(x.x, w0, a);
                a = fmaf(x.y, w1, a);
                a = fmaf(x.z, w2, a);
                a = fmaf(x.w, w3, a);
                acc[i] = a;
            }
        }
        __syncthreads();
        #pragma unroll
        for (int i = 0; i < 4; ++i) {
            const float x = acc[i];
            sA[rg + 2 * i][c] = 0.5f * x * (1.f + erff(x * 0.70710678118654752f));
        }
    }
    __syncthreads();
    {   // FFN2 + residual + masked column sum
        float acc[4];
        const float bb = b2[c];
        #pragma unroll
        for (int i = 0; i < 4; ++i) acc[i] = bb;
        #pragma unroll 8
        for (int k = 0; k < 128; k += 4) {
            const float w0 = W2[(k + 0) * 128 + c];
            const float w1 = W2[(k + 1) * 128 + c];
            const float w2 = W2[(k + 2) * 128 + c];
            const float w3 = W2[(k + 3) * 128 + c];
            #pragma unroll
            for (int i = 0; i < 4; ++i) {
                const float4 x = *(const float4*)&sA[rg + 2 * i][k];
                float a = acc[i];
                a = fmaf(x.x, w0, a);
                a = fmaf(x.y, w1, a);
                a = fmaf(x.z, w2, a);
                a = fmaf(x.w, w3, a);
                acc[i] = a;
            }
        }
        const int nsel = sele[0];
        float local = 0.f;
        #pragma unroll
        for (int i = 0; i < 4; ++i) {
            const float ef = x2[rg + 2 * i][c] + acc[i];
            if (r0 + rg + 2 * i < nsel) local += ef;
        }
        colsum[rg][c] = local;
    }
    __syncthreads();
    if (rg == 0) atomicAdd(&xsum[c], colsum[0][c] + colsum[1][c]);
}

// ---------------- K5: pooled coefficients ----------------
__global__ __launch_bounds__(128) void k_coef(const float* __restrict__ xsum,
    const float* __restrict__ dscW, const float* __restrict__ dscb,
    const float* __restrict__ dwvW, const float* __restrict__ dwvb,
    const float* __restrict__ dssW, const float* __restrict__ dssb,
    const int* __restrict__ len, const int* __restrict__ sele,
    float* __restrict__ coef)
{
    __shared__ float xs[128];
    __shared__ float csc[50], cwv[50];
    __shared__ float s2[2];
    const int t = threadIdx.x;
    xs[t] = xsum[t];
    __syncthreads();
    const float invl = 1.f / ((float)len[0] + 1e-8f);
    const float ns = (float)sele[0];
    if (t < 50) {
        float a = ns * dscb[t];
        for (int k = 0; k < 128; ++k) a = fmaf(xs[k], dscW[k * 50 + t], a);
        a *= invl;
        csc[t] = 1.f / (1.f + expf(-a));
    } else if (t >= 64 && t < 114) {
        const int j = t - 64;
        float a = ns * dwvb[j];
        for (int k = 0; k < 128; ++k) a = fmaf(xs[k], dwvW[k * 50 + j], a);
        a *= invl;
        cwv[j] = 1.f / (1.f + expf(-a));
    } else if (t >= 114 && t < 118) {
        const int j = t - 114;
        float a = ns * dssb[j];
        for (int k = 0; k < 128; ++k) a = fmaf(xs[k], dssW[k * 4 + j], a);
        a *= invl;
        coef[100 + j] = (1.f / (1.f + expf(-a))) * 5.0f;  // THRE
    }
    __syncthreads();
    if (t == 0) { float s = 0.f; for (int i2 = 0; i2 < 50; ++i2) s += csc[i2]; s2[0] = s; }
    if (t == 1) { float s = 0.f; for (int i2 = 0; i2 < 50; ++i2) s += cwv[i2]; s2[1] = s; }
    __syncthreads();
    if (t < 50) {
        coef[t]      = csc[t] / (s2[0] + 1e-8f);
        coef[50 + t] = cwv[t] / (s2[1] + 1e-8f);
    }
}

// ---------------- K6: Chebyshev bases + combine + normalize ----------------
__global__ __launch_bounds__(256) void k_out(const float* __restrict__ eve,
    const float* __restrict__ coef, float* __restrict__ out)
{
    __shared__ float csc[50], cwv[50], cs[4];
    const int t = threadIdx.x;
    if (t < 50) csc[t] = coef[t];
    else if (t < 100) cwv[t - 50] = coef[t];
    else if (t < 104) cs[t - 100] = coef[t];
    __syncthreads();
    const int s = blockIdx.x * 256 + t;
    const float e = eve[s];
    float vals[5];
    {   // scaling: [T1, T3, ..., T99](e-1); 0.5*(1-T)
        const float y = e - 1.f;
        float te = 1.f, to = y;
        float a = csc[0] * (0.5f * (1.f - to));
        const float y2 = 2.f * y;
        for (int i = 1; i < 50; ++i) {
            te = fmaf(y2, to, -te);
            to = fmaf(y2, te, -to);
            a = fmaf(csc[i], 0.5f * (1.f - to), a);
        }
        vals[0] = a;
    }
    #pragma unroll
    for (int j = 0; j < 4; ++j) {  // wavelet: [T0, T2, ..., T98](fsw-1)
        float f = e * cs[j];
        if (f > 2.f) f = 0.f;
        const float y = f - 1.f;
        float te = 1.f, to = y;
        float a = cwv[0] * (0.5f * (1.f - te));
        const float y2 = 2.f * y;
        for (int i = 1; i < 50; ++i) {
            te = fmaf(y2, to, -te);
            to = fmaf(y2, te, -to);
            a = fmaf(cwv[i], 0.5f * (1.f - te), a);
        }
        vals[1 + j] = a;
    }
    float n2 = 0.f;
    #pragma unroll
    for (int k = 0; k < 5; ++k) n2 += vals[k] * vals[k];
    const float invn = 1.f / (sqrtf(n2) + 1e-8f);
    #pragma unroll
    for (int k = 0; k < 5; ++k) out[s * 5 + k] = vals[k] * invn;
}

extern "C" void kernel_launch(void* const* d_in, const int* in_sizes, int n_in,
                              void* d_out, int out_size, void* d_ws, size_t ws_size,
                              hipStream_t stream) {
    const float* eve  = (const float*)d_in[0];
    const int*   len  = (const int*)d_in[1];
    const int*   sele = (const int*)d_in[2];
    const float* eigW = (const float*)d_in[3];
    const float* eigB = (const float*)d_in[4];
    const float* mlg  = (const float*)d_in[5];
    const float* mlb  = (const float*)d_in[6];
    const float* inW  = (const float*)d_in[7];
    const float* inb  = (const float*)d_in[8];
    const float* outW = (const float*)d_in[9];
    const float* outb = (const float*)d_in[10];
    const float* flg  = (const float*)d_in[11];
    const float* flb  = (const float*)d_in[12];
    const float* W1   = (const float*)d_in[13];
    const float* b1   = (const float*)d_in[14];
    const float* W2   = (const float*)d_in[15];
    const float* b2   = (const float*)d_in[16];
    const float* dscW = (const float*)d_in[17];
    const float* dscb = (const float*)d_in[18];
    const float* dwvW = (const float*)d_in[19];
    const float* dwvb = (const float*)d_in[20];
    const float* dssW = (const float*)d_in[21];
    const float* dssb = (const float*)d_in[22];

    float* ws   = (float*)d_ws;
    float* eig  = ws;
    float* qkv  = ws + 524288;
    float* Oe   = ws + 2097152;
    float* E    = ws + 4194304;
    float* xsum = ws + 4259840;
    float* coef = ws + 4259968;
    unsigned short* Khi_g = (unsigned short*)(ws + 4260352);
    unsigned short* Klo_g = (unsigned short*)(ws + 4522496);
    unsigned short* Vt_g  = (unsigned short*)(ws + 4784640);
    float* out  = (float*)d_out;

    hipMemsetAsync(xsum, 0, 128 * sizeof(float), stream);
    k_eig <<<512, 256, 0, stream>>>(eve, eigW, eigB, eig);
    k_qkv <<<512, 256, 0, stream>>>(eig, mlg, mlb, inW, inb, qkv, Khi_g, Klo_g, Vt_g);
    k_attn<<<dim3(64, 4, KSPLIT), 256, 0, stream>>>(qkv, Khi_g, Klo_g, Vt_g, sele, Oe, E);
    k_ffn <<<512, 256, 0, stream>>>(eig, Oe, E, outW, outb, flg, flb, W1, b1, W2, b2, sele, xsum);
    k_coef<<<1, 128, 0, stream>>>(xsum, dscW, dscb, dwvW, dwvb, dssW, dssb, len, sele, coef);
    k_out <<<16, 256, 0, stream>>>(eve, coef, out);
}